// Round 2
// baseline (3366.018 us; speedup 1.0000x reference)
//
#include <hip/hip_runtime.h>
#include <hip/hip_bf16.h>

// ---------------------------------------------------------------------------
// QuadraticGNN: 3x ResGatedGraphConv (ReLU gate, LeakyReLU 0.01, linear Wl)
//               -> global mean pool (32 graphs) -> 5-layer MLP with BN.
// Round 1: fp32, lean workspace (~179 MB) via 64-channel chunking.
//   - Layers process co in chunks of 64: K/Q/V/agg are N x 64 buffers.
//   - Wl GEMM accumulates over chunks (leaky applied on A-load).
//   - Layer 3: pool commutes with Wl (linear) -> pool leaky(h1) into [32,256],
//     apply Wl3 inside the MLP kernel. Saves N x 256 buffer + 13 GFLOP GEMM.
// ---------------------------------------------------------------------------

#define GN_N 100000
#define GN_E 300000
#define GN_G 32

// C[:, col0:col0+64*gridy] (+)= act(A)[N,K] @ W[K, cols] + bias
// A: ld lda. W: ld ldw (pre-offset to col/row start by host). C: ld ldc.
__global__ __launch_bounds__(256) void sgemm(
    const float* __restrict__ A, int lda,
    const float* __restrict__ W, int ldw,
    const float* __restrict__ bias,
    float* __restrict__ C, int ldc,
    int N, int K, int leaky, int accum)
{
    alignas(16) __shared__ float As[16][68];
    alignas(16) __shared__ float Bs[16][68];
    int tid  = threadIdx.x;
    int row0 = blockIdx.x * 64;
    int col0 = blockIdx.y * 64;
    int tx = tid & 15, ty = tid >> 4;

    float acc[4][4] = {};

    for (int k0 = 0; k0 < K; k0 += 16) {
        {   // A tile: 64 rows x 16 k (one float4 per thread)
            int r  = tid >> 2;
            int kq = (tid & 3) * 4;
            int row = row0 + r;
            float4 a = make_float4(0.f, 0.f, 0.f, 0.f);
            if (row < N) a = *(const float4*)(A + (long long)row * lda + k0 + kq);
            if (leaky) {
                a.x = a.x > 0.f ? a.x : 0.01f * a.x;
                a.y = a.y > 0.f ? a.y : 0.01f * a.y;
                a.z = a.z > 0.f ? a.z : 0.01f * a.z;
                a.w = a.w > 0.f ? a.w : 0.01f * a.w;
            }
            As[kq + 0][r] = a.x; As[kq + 1][r] = a.y;
            As[kq + 2][r] = a.z; As[kq + 3][r] = a.w;
        }
        {   // W tile: 16 k x 64 cols
            int kk = tid >> 4;
            int c4 = (tid & 15) * 4;
            float4 b = *(const float4*)(W + (long long)(k0 + kk) * ldw + col0 + c4);
            *(float4*)&Bs[kk][c4] = b;
        }
        __syncthreads();
        #pragma unroll
        for (int k = 0; k < 16; ++k) {
            float a[4], b[4];
            #pragma unroll
            for (int i = 0; i < 4; ++i) a[i] = As[k][ty * 4 + i];
            #pragma unroll
            for (int j = 0; j < 4; ++j) b[j] = Bs[k][tx * 4 + j];
            #pragma unroll
            for (int i = 0; i < 4; ++i)
                #pragma unroll
                for (int j = 0; j < 4; ++j)
                    acc[i][j] += a[i] * b[j];
        }
        __syncthreads();
    }

    float4 bb = make_float4(0.f, 0.f, 0.f, 0.f);
    if (!accum) bb = *(const float4*)(bias + col0 + tx * 4);
    #pragma unroll
    for (int i = 0; i < 4; ++i) {
        int row = row0 + ty * 4 + i;
        if (row >= N) continue;
        float* cp = C + (long long)row * ldc + col0 + tx * 4;
        float4 o;
        o.x = acc[i][0] + bb.x;
        o.y = acc[i][1] + bb.y;
        o.z = acc[i][2] + bb.z;
        o.w = acc[i][3] + bb.w;
        if (accum) {
            float4 old = *(float4*)cp;
            o.x += old.x; o.y += old.y; o.z += old.z; o.w += old.w;
        }
        *(float4*)cp = o;
    }
}

// One 64-channel chunk. K/Q/V/agg are [N,64].
__global__ __launch_bounds__(256) void edge_chunk(
    const float* __restrict__ K, const float* __restrict__ Q,
    const float* __restrict__ V, float* __restrict__ agg,
    const int* __restrict__ src, const int* __restrict__ dst, int E)
{
    int idx = blockIdx.x * 256 + threadIdx.x;
    if (idx >= E * 16) return;
    int e = idx >> 4;
    int c4 = (idx & 15) << 2;
    int s = src[e], d = dst[e];
    const float4 k = *(const float4*)(K + d * 64 + c4);
    const float4 q = *(const float4*)(Q + s * 64 + c4);
    const float4 v = *(const float4*)(V + s * 64 + c4);
    float* ap = agg + d * 64 + c4;
    float g;
    g = k.x + q.x; if (g > 0.f) atomicAdd(ap + 0, g * v.x);
    g = k.y + q.y; if (g > 0.f) atomicAdd(ap + 1, g * v.y);
    g = k.z + q.z; if (g > 0.f) atomicAdd(ap + 2, g * v.z);
    g = k.w + q.w; if (g > 0.f) atomicAdd(ap + 3, g * v.w);
}

__global__ void zero_kernel(float* sums, float* cnt)
{
    int i = blockIdx.x * 256 + threadIdx.x;
    if (i < GN_G * 256) sums[i] = 0.0f;
    else if (i < GN_G * 256 + GN_G) cnt[i - GN_G * 256] = 0.0f;
}

// Pool leaky(agg_chunk) into sums[:, c0:c0+64]. batch sorted ascending.
// Block = 64 threads (one wave) = 64 channels; 512 nodes per block.
__global__ __launch_bounds__(64) void pool_chunk(
    const float* __restrict__ agg, const int* __restrict__ batch,
    float* __restrict__ sums, float* __restrict__ cnt, int c0, int do_cnt)
{
    int c = threadIdx.x;
    int start = blockIdx.x * 512;
    if (start >= GN_N) return;
    int end = min(start + 512, GN_N);
    float acc = 0.0f, n = 0.0f;
    int curg = batch[start];
    for (int node = start; node < end; ++node) {
        int g = batch[node];
        if (g != curg) {
            atomicAdd(&sums[curg * 256 + c0 + c], acc);
            if (do_cnt && c == 0) atomicAdd(&cnt[curg], n);
            acc = 0.0f; n = 0.0f; curg = g;
        }
        float v = agg[(long long)node * 64 + c];
        v = v > 0.f ? v : 0.01f * v;
        acc += v; n += 1.0f;
    }
    atomicAdd(&sums[curg * 256 + c0 + c], acc);
    if (do_cnt && c == 0) atomicAdd(&cnt[curg], n);
}

// Single block: Pl = sums/cnt; Pg = Pl @ Wl3 + bl3; then BN-MLP chain.
__global__ __launch_bounds__(256) void mlp_kernel(
    const float* __restrict__ sums, const float* __restrict__ cnt,
    const float* __restrict__ Wl3, const float* __restrict__ bl3,
    const float* __restrict__ W1, const float* __restrict__ b1,
    const float* __restrict__ Wh, const float* __restrict__ bh,
    const float* __restrict__ Wo, const float* __restrict__ bo,
    const float* __restrict__ gamma, const float* __restrict__ beta,
    const float* __restrict__ mean, const float* __restrict__ var,
    float* __restrict__ out)
{
    __shared__ float buf[GN_G * 256];   // 32 KB
    __shared__ float sh[2][GN_G * 64];  // 16 KB
    int t = threadIdx.x;

    for (int i = t; i < GN_G * 256; i += 256) {
        int g = i >> 8;
        buf[i] = sums[i] / fmaxf(cnt[g], 1.0f);
    }
    __syncthreads();

    // Pg[g, m=t] for all 32 graphs, in registers; then write back in place.
    {
        float pg[GN_G];
        #pragma unroll 4
        for (int g = 0; g < GN_G; ++g) {
            float acc = bl3[t];
            for (int k = 0; k < 256; ++k)
                acc += buf[g * 256 + k] * Wl3[k * 256 + t];
            pg[g] = acc;
        }
        __syncthreads();
        for (int g = 0; g < GN_G; ++g) buf[g * 256 + t] = pg[g];
        __syncthreads();
    }

    // layer 1: [32,256] @ [256,64] -> bn0 -> relu
    for (int i = t; i < GN_G * 64; i += 256) {
        int g = i >> 6, c = i & 63;
        float acc = b1[c];
        for (int k = 0; k < 256; ++k) acc += buf[g * 256 + k] * W1[k * 64 + c];
        float sc = gamma[c] * rsqrtf(var[c] + 1e-5f);
        acc = (acc - mean[c]) * sc + beta[c];
        sh[0][i] = fmaxf(acc, 0.0f);
    }
    __syncthreads();

    int cur = 0;
    for (int L = 0; L < 3; ++L) {
        const float* W  = Wh + L * 64 * 64;
        const float* b  = bh + L * 64;
        const float* ga = gamma + (L + 1) * 64;
        const float* be = beta  + (L + 1) * 64;
        const float* me = mean  + (L + 1) * 64;
        const float* va = var   + (L + 1) * 64;
        for (int i = t; i < GN_G * 64; i += 256) {
            int g = i >> 6, c = i & 63;
            float acc = b[c];
            for (int k = 0; k < 64; ++k) acc += sh[cur][g * 64 + k] * W[k * 64 + c];
            float sc = ga[c] * rsqrtf(va[c] + 1e-5f);
            acc = (acc - me[c]) * sc + be[c];
            sh[1 - cur][i] = fmaxf(acc, 0.0f);
        }
        cur = 1 - cur;
        __syncthreads();
    }

    {
        int g = t >> 3, c = t & 7;   // 256 threads == 32*8 outputs
        float acc = bo[c];
        for (int k = 0; k < 64; ++k) acc += sh[cur][g * 64 + k] * Wo[k * 8 + c];
        out[g * 8 + c] = acc;
    }
}

extern "C" void kernel_launch(void* const* d_in, const int* in_sizes, int n_in,
                              void* d_out, int out_size, void* d_ws, size_t ws_size,
                              hipStream_t stream)
{
    const int N = GN_N, E = GN_E;
    const float* x          = (const float*)d_in[0];
    const int*   edge_index = (const int*)d_in[1];
    const int*   batch      = (const int*)d_in[2];
    const int*   src = edge_index;
    const int*   dst = edge_index + E;

    // Workspace layout (floats): total 44,808,224 floats = ~179.2 MB
    const size_t NB = (size_t)N * 64;
    float* ws   = (float*)d_ws;
    float* Kb   = ws;
    float* Qb   = Kb  + NB;
    float* Vb   = Qb  + NB;
    float* agg  = Vb  + NB;
    float* hA   = agg + NB;            // layer1 out: N x 64
    float* hB   = hA  + NB;            // layer2 out: N x 128
    float* sums = hB  + (size_t)N * 128;
    float* cnt  = sums + GN_G * 256;

    size_t need = ((size_t)(cnt + GN_G) - (size_t)ws);
    if (ws_size < need) return;  // diagnostic: absmax will equal stub value

    auto F = [&](int i) { return (const float*)d_in[i]; };
    struct Layer {
        int ci, co;
        const float *Wk, *Wq, *Wv, *Ws, *bk, *bq, *bv, *bs, *Wl, *bl;
        const float* hin;
        float* hout;
    };
    Layer layers[3] = {
        {128,  64, F(3),  F(4),  F(5),  F(6),  F(7),  F(8),  F(9),  F(10), F(11), F(12), x,  hA},
        { 64, 128, F(13), F(14), F(15), F(16), F(17), F(18), F(19), F(20), F(21), F(22), hA, hB},
        {128, 256, F(23), F(24), F(25), F(26), F(27), F(28), F(29), F(30), F(31), F(32), hB, nullptr},
    };

    const int rowTiles = (N + 63) / 64;
    const int edgeBlocks = (E * 16 + 255) / 256;

    zero_kernel<<<(GN_G * 256 + GN_G + 255) / 256, 256, 0, stream>>>(sums, cnt);

    for (int l = 0; l < 3; ++l) {
        Layer& L = layers[l];
        int nch = L.co / 64;
        for (int ch = 0; ch < nch; ++ch) {
            int c0 = ch * 64;
            dim3 g1(rowTiles, 1);
            sgemm<<<g1, 256, 0, stream>>>(L.hin, L.ci, L.Wk + c0, L.co, L.bk + c0, Kb,  64, N, L.ci, 0, 0);
            sgemm<<<g1, 256, 0, stream>>>(L.hin, L.ci, L.Wq + c0, L.co, L.bq + c0, Qb,  64, N, L.ci, 0, 0);
            sgemm<<<g1, 256, 0, stream>>>(L.hin, L.ci, L.Wv + c0, L.co, L.bv + c0, Vb,  64, N, L.ci, 0, 0);
            sgemm<<<g1, 256, 0, stream>>>(L.hin, L.ci, L.Ws + c0, L.co, L.bs + c0, agg, 64, N, L.ci, 0, 0);

            edge_chunk<<<edgeBlocks, 256, 0, stream>>>(Kb, Qb, Vb, agg, src, dst, E);

            if (l < 2) {
                // hout[:, :] (+)= leaky(agg)[N,64] @ Wl[c0:c0+64, :co] (+ bl)
                dim3 g2(rowTiles, L.co / 64);
                sgemm<<<g2, 256, 0, stream>>>(agg, 64, L.Wl + (size_t)c0 * L.co, L.co,
                                              L.bl, L.hout, L.co, N, 64, 1, ch > 0);
            } else {
                pool_chunk<<<(N + 511) / 512, 64, 0, stream>>>(agg, batch, sums, cnt, c0, ch == 0);
            }
        }
    }

    mlp_kernel<<<1, 256, 0, stream>>>(sums, cnt, F(31), F(32),
                                      F(33), F(34), F(35), F(36), F(37), F(38),
                                      F(39), F(40), F(41), F(42),
                                      (float*)d_out);
}

// Round 3
// 2319.150 us; speedup vs baseline: 1.4514x; 1.4514x over previous
//
#include <hip/hip_runtime.h>
#include <hip/hip_bf16.h>

// ---------------------------------------------------------------------------
// QuadraticGNN: 3x ResGatedGraphConv (ReLU gate, LeakyReLU 0.01, linear Wl)
//               -> global mean pool (32 graphs) -> 5-layer MLP with BN.
// Round 2: replace scatter-atomic edge phase with gather-over-CSR.
//   - CSR (by dst) built once per call: histogram + 1-block scan + scatter.
//   - edge_gather: 1 wave per node, registers accumulate, streaming write.
//     Kills atomic RMW write amplification (238 MB -> ~26 MB per pass).
//   - Rest unchanged from round 1 (fp32 sgemm, chunked channels, pooled Wl3).
// ---------------------------------------------------------------------------

#define GN_N 100000
#define GN_E 300000
#define GN_G 32

// C[:, col0:col0+64*gridy] (+)= act(A)[N,K] @ W[K, cols] + bias
__global__ __launch_bounds__(256) void sgemm(
    const float* __restrict__ A, int lda,
    const float* __restrict__ W, int ldw,
    const float* __restrict__ bias,
    float* __restrict__ C, int ldc,
    int N, int K, int leaky, int accum)
{
    alignas(16) __shared__ float As[16][68];
    alignas(16) __shared__ float Bs[16][68];
    int tid  = threadIdx.x;
    int row0 = blockIdx.x * 64;
    int col0 = blockIdx.y * 64;
    int tx = tid & 15, ty = tid >> 4;

    float acc[4][4] = {};

    for (int k0 = 0; k0 < K; k0 += 16) {
        {   // A tile: 64 rows x 16 k (one float4 per thread)
            int r  = tid >> 2;
            int kq = (tid & 3) * 4;
            int row = row0 + r;
            float4 a = make_float4(0.f, 0.f, 0.f, 0.f);
            if (row < N) a = *(const float4*)(A + (long long)row * lda + k0 + kq);
            if (leaky) {
                a.x = a.x > 0.f ? a.x : 0.01f * a.x;
                a.y = a.y > 0.f ? a.y : 0.01f * a.y;
                a.z = a.z > 0.f ? a.z : 0.01f * a.z;
                a.w = a.w > 0.f ? a.w : 0.01f * a.w;
            }
            As[kq + 0][r] = a.x; As[kq + 1][r] = a.y;
            As[kq + 2][r] = a.z; As[kq + 3][r] = a.w;
        }
        {   // W tile: 16 k x 64 cols
            int kk = tid >> 4;
            int c4 = (tid & 15) * 4;
            float4 b = *(const float4*)(W + (long long)(k0 + kk) * ldw + col0 + c4);
            *(float4*)&Bs[kk][c4] = b;
        }
        __syncthreads();
        #pragma unroll
        for (int k = 0; k < 16; ++k) {
            float a[4], b[4];
            #pragma unroll
            for (int i = 0; i < 4; ++i) a[i] = As[k][ty * 4 + i];
            #pragma unroll
            for (int j = 0; j < 4; ++j) b[j] = Bs[k][tx * 4 + j];
            #pragma unroll
            for (int i = 0; i < 4; ++i)
                #pragma unroll
                for (int j = 0; j < 4; ++j)
                    acc[i][j] += a[i] * b[j];
        }
        __syncthreads();
    }

    float4 bb = make_float4(0.f, 0.f, 0.f, 0.f);
    if (!accum) bb = *(const float4*)(bias + col0 + tx * 4);
    #pragma unroll
    for (int i = 0; i < 4; ++i) {
        int row = row0 + ty * 4 + i;
        if (row >= N) continue;
        float* cp = C + (long long)row * ldc + col0 + tx * 4;
        float4 o;
        o.x = acc[i][0] + bb.x;
        o.y = acc[i][1] + bb.y;
        o.z = acc[i][2] + bb.z;
        o.w = acc[i][3] + bb.w;
        if (accum) {
            float4 old = *(float4*)cp;
            o.x += old.x; o.y += old.y; o.z += old.z; o.w += old.w;
        }
        *(float4*)cp = o;
    }
}

// ---------------- CSR build (by dst), once per call ----------------
__global__ void zero_int(int* p, int n)
{
    int i = blockIdx.x * 256 + threadIdx.x;
    if (i < n) p[i] = 0;
}

__global__ void hist_kernel(const int* __restrict__ dst, int* __restrict__ deg)
{
    int e = blockIdx.x * 256 + threadIdx.x;
    if (e < GN_E) atomicAdd(&deg[dst[e]], 1);
}

// Single block, 1024 threads: exclusive scan of deg[N] -> row_ptr & cursor.
__global__ __launch_bounds__(1024) void scan_kernel(
    const int* __restrict__ deg, int* __restrict__ row_ptr, int* __restrict__ cursor)
{
    __shared__ int bsum[1024];
    int t = threadIdx.x;
    const int per = (GN_N + 1023) / 1024;
    int base = t * per;
    int s = 0;
    for (int i = 0; i < per; ++i) {
        int idx = base + i;
        if (idx < GN_N) s += deg[idx];
    }
    bsum[t] = s;
    __syncthreads();
    for (int off = 1; off < 1024; off <<= 1) {
        int v = (t >= off) ? bsum[t - off] : 0;
        __syncthreads();
        bsum[t] += v;
        __syncthreads();
    }
    int run = (t == 0) ? 0 : bsum[t - 1];
    for (int i = 0; i < per; ++i) {
        int idx = base + i;
        if (idx < GN_N) {
            row_ptr[idx] = run;
            cursor[idx] = run;
            run += deg[idx];
        }
    }
    if (t == 1023) row_ptr[GN_N] = run;
}

__global__ void scatter_kernel(
    const int* __restrict__ src, const int* __restrict__ dst,
    int* __restrict__ cursor, int* __restrict__ elist)
{
    int e = blockIdx.x * 256 + threadIdx.x;
    if (e >= GN_E) return;
    int d = dst[e];
    int pos = atomicAdd(&cursor[d], 1);
    elist[pos] = src[e];
}

// ---------------- edge gather: agg[d] = Sx[d] + sum_{s->d} relu(K[d]+Q[s])*V[s]
// One wave (64 lanes = 64 channels) per node; agg updated in place.
__global__ __launch_bounds__(256) void edge_gather(
    const float* __restrict__ K, const float* __restrict__ Q,
    const float* __restrict__ V, float* __restrict__ agg,
    const int* __restrict__ row_ptr, const int* __restrict__ elist)
{
    int node = blockIdx.x * 4 + (threadIdx.x >> 6);
    if (node >= GN_N) return;
    int c = threadIdx.x & 63;
    int beg = row_ptr[node];
    int end = row_ptr[node + 1];
    float k   = K[node * 64 + c];
    float acc = agg[node * 64 + c];
    for (int i = beg; i < end; ++i) {
        int s = elist[i];
        float q = Q[s * 64 + c];
        float v = V[s * 64 + c];
        float g = k + q;
        if (g > 0.f) acc += g * v;
    }
    agg[node * 64 + c] = acc;
}

__global__ void zero_kernel(float* sums, float* cnt)
{
    int i = blockIdx.x * 256 + threadIdx.x;
    if (i < GN_G * 256) sums[i] = 0.0f;
    else if (i < GN_G * 256 + GN_G) cnt[i - GN_G * 256] = 0.0f;
}

// Pool leaky(agg_chunk) into sums[:, c0:c0+64]. batch sorted ascending.
__global__ __launch_bounds__(64) void pool_chunk(
    const float* __restrict__ agg, const int* __restrict__ batch,
    float* __restrict__ sums, float* __restrict__ cnt, int c0, int do_cnt)
{
    int c = threadIdx.x;
    int start = blockIdx.x * 512;
    if (start >= GN_N) return;
    int end = min(start + 512, GN_N);
    float acc = 0.0f, n = 0.0f;
    int curg = batch[start];
    for (int node = start; node < end; ++node) {
        int g = batch[node];
        if (g != curg) {
            atomicAdd(&sums[curg * 256 + c0 + c], acc);
            if (do_cnt && c == 0) atomicAdd(&cnt[curg], n);
            acc = 0.0f; n = 0.0f; curg = g;
        }
        float v = agg[(long long)node * 64 + c];
        v = v > 0.f ? v : 0.01f * v;
        acc += v; n += 1.0f;
    }
    atomicAdd(&sums[curg * 256 + c0 + c], acc);
    if (do_cnt && c == 0) atomicAdd(&cnt[curg], n);
}

// Single block: Pl = sums/cnt; Pg = Pl @ Wl3 + bl3; then BN-MLP chain.
__global__ __launch_bounds__(256) void mlp_kernel(
    const float* __restrict__ sums, const float* __restrict__ cnt,
    const float* __restrict__ Wl3, const float* __restrict__ bl3,
    const float* __restrict__ W1, const float* __restrict__ b1,
    const float* __restrict__ Wh, const float* __restrict__ bh,
    const float* __restrict__ Wo, const float* __restrict__ bo,
    const float* __restrict__ gamma, const float* __restrict__ beta,
    const float* __restrict__ mean, const float* __restrict__ var,
    float* __restrict__ out)
{
    __shared__ float buf[GN_G * 256];   // 32 KB
    __shared__ float sh[2][GN_G * 64];  // 16 KB
    int t = threadIdx.x;

    for (int i = t; i < GN_G * 256; i += 256) {
        int g = i >> 8;
        buf[i] = sums[i] / fmaxf(cnt[g], 1.0f);
    }
    __syncthreads();

    {
        float pg[GN_G];
        #pragma unroll 4
        for (int g = 0; g < GN_G; ++g) {
            float acc = bl3[t];
            for (int k = 0; k < 256; ++k)
                acc += buf[g * 256 + k] * Wl3[k * 256 + t];
            pg[g] = acc;
        }
        __syncthreads();
        for (int g = 0; g < GN_G; ++g) buf[g * 256 + t] = pg[g];
        __syncthreads();
    }

    for (int i = t; i < GN_G * 64; i += 256) {
        int g = i >> 6, c = i & 63;
        float acc = b1[c];
        for (int k = 0; k < 256; ++k) acc += buf[g * 256 + k] * W1[k * 64 + c];
        float sc = gamma[c] * rsqrtf(var[c] + 1e-5f);
        acc = (acc - mean[c]) * sc + beta[c];
        sh[0][i] = fmaxf(acc, 0.0f);
    }
    __syncthreads();

    int cur = 0;
    for (int L = 0; L < 3; ++L) {
        const float* W  = Wh + L * 64 * 64;
        const float* b  = bh + L * 64;
        const float* ga = gamma + (L + 1) * 64;
        const float* be = beta  + (L + 1) * 64;
        const float* me = mean  + (L + 1) * 64;
        const float* va = var   + (L + 1) * 64;
        for (int i = t; i < GN_G * 64; i += 256) {
            int g = i >> 6, c = i & 63;
            float acc = b[c];
            for (int k = 0; k < 64; ++k) acc += sh[cur][g * 64 + k] * W[k * 64 + c];
            float sc = ga[c] * rsqrtf(va[c] + 1e-5f);
            acc = (acc - me[c]) * sc + be[c];
            sh[1 - cur][i] = fmaxf(acc, 0.0f);
        }
        cur = 1 - cur;
        __syncthreads();
    }

    {
        int g = t >> 3, c = t & 7;
        float acc = bo[c];
        for (int k = 0; k < 64; ++k) acc += sh[cur][g * 64 + k] * Wo[k * 8 + c];
        out[g * 8 + c] = acc;
    }
}

extern "C" void kernel_launch(void* const* d_in, const int* in_sizes, int n_in,
                              void* d_out, int out_size, void* d_ws, size_t ws_size,
                              hipStream_t stream)
{
    const int N = GN_N, E = GN_E;
    const float* x          = (const float*)d_in[0];
    const int*   edge_index = (const int*)d_in[1];
    const int*   batch      = (const int*)d_in[2];
    const int*   src = edge_index;
    const int*   dst = edge_index + E;

    // Workspace layout: floats then ints (~181 MB total)
    const size_t NB = (size_t)N * 64;
    float* ws   = (float*)d_ws;
    float* Kb   = ws;
    float* Qb   = Kb  + NB;
    float* Vb   = Qb  + NB;
    float* agg  = Vb  + NB;
    float* hA   = agg + NB;            // layer1 out: N x 64
    float* hB   = hA  + NB;            // layer2 out: N x 128
    float* sums = hB  + (size_t)N * 128;
    float* cnt  = sums + GN_G * 256;
    int*   deg     = (int*)(cnt + GN_G);
    int*   cursor  = deg + N;
    int*   row_ptr = cursor + N;       // N+1
    int*   elist   = row_ptr + (N + 1);

    size_t need = ((size_t)(elist + E) - (size_t)ws);
    if (ws_size < need) return;

    auto F = [&](int i) { return (const float*)d_in[i]; };
    struct Layer {
        int ci, co;
        const float *Wk, *Wq, *Wv, *Ws, *bk, *bq, *bv, *bs, *Wl, *bl;
        const float* hin;
        float* hout;
    };
    Layer layers[3] = {
        {128,  64, F(3),  F(4),  F(5),  F(6),  F(7),  F(8),  F(9),  F(10), F(11), F(12), x,  hA},
        { 64, 128, F(13), F(14), F(15), F(16), F(17), F(18), F(19), F(20), F(21), F(22), hA, hB},
        {128, 256, F(23), F(24), F(25), F(26), F(27), F(28), F(29), F(30), F(31), F(32), hB, nullptr},
    };

    const int rowTiles = (N + 63) / 64;
    const int eb = (E + 255) / 256;

    // Build CSR by dst
    zero_int<<<(N + 255) / 256, 256, 0, stream>>>(deg, N);
    hist_kernel<<<eb, 256, 0, stream>>>(dst, deg);
    scan_kernel<<<1, 1024, 0, stream>>>(deg, row_ptr, cursor);
    scatter_kernel<<<eb, 256, 0, stream>>>(src, dst, cursor, elist);

    zero_kernel<<<(GN_G * 256 + GN_G + 255) / 256, 256, 0, stream>>>(sums, cnt);

    const int gatherBlocks = (N + 3) / 4;
    for (int l = 0; l < 3; ++l) {
        Layer& L = layers[l];
        int nch = L.co / 64;
        for (int ch = 0; ch < nch; ++ch) {
            int c0 = ch * 64;
            dim3 g1(rowTiles, 1);
            sgemm<<<g1, 256, 0, stream>>>(L.hin, L.ci, L.Wk + c0, L.co, L.bk + c0, Kb,  64, N, L.ci, 0, 0);
            sgemm<<<g1, 256, 0, stream>>>(L.hin, L.ci, L.Wq + c0, L.co, L.bq + c0, Qb,  64, N, L.ci, 0, 0);
            sgemm<<<g1, 256, 0, stream>>>(L.hin, L.ci, L.Wv + c0, L.co, L.bv + c0, Vb,  64, N, L.ci, 0, 0);
            sgemm<<<g1, 256, 0, stream>>>(L.hin, L.ci, L.Ws + c0, L.co, L.bs + c0, agg, 64, N, L.ci, 0, 0);

            edge_gather<<<gatherBlocks, 256, 0, stream>>>(Kb, Qb, Vb, agg, row_ptr, elist);

            if (l < 2) {
                dim3 g2(rowTiles, L.co / 64);
                sgemm<<<g2, 256, 0, stream>>>(agg, 64, L.Wl + (size_t)c0 * L.co, L.co,
                                              L.bl, L.hout, L.co, N, 64, 1, ch > 0);
            } else {
                pool_chunk<<<(N + 511) / 512, 64, 0, stream>>>(agg, batch, sums, cnt, c0, ch == 0);
            }
        }
    }

    mlp_kernel<<<1, 256, 0, stream>>>(sums, cnt, F(31), F(32),
                                      F(33), F(34), F(35), F(36), F(37), F(38),
                                      F(39), F(40), F(41), F(42),
                                      (float*)d_out);
}

// Round 4
// 1813.996 us; speedup vs baseline: 1.8556x; 1.2785x over previous
//
#include <hip/hip_runtime.h>
#include <hip/hip_bf16.h>

// ---------------------------------------------------------------------------
// QuadraticGNN: 3x ResGatedGraphConv (ReLU gate, LeakyReLU 0.01, linear Wl)
//               -> global mean pool (32 graphs) -> 5-layer MLP with BN.
// Round 3:
//   - Hierarchical 3-kernel scan (was: 268us single-block scan).
//   - ALL GEMMs via MFMA bf16 3-term emulation (hi*hi + hi*lo + lo*hi),
//     fp32 accumulate -> fp32-grade accuracy at matrix-core rates.
//     Weights pre-converted once per call to k-major bf16 hi/lo in ws.
//   - Gates fused: one launch computes [K|Q|V|S] into G[N,256]; edge_gather
//     runs in-place on G; Wl / pool read the S-section (stride 256).
// ---------------------------------------------------------------------------

#define GN_N 100000
#define GN_E 300000
#define GN_G 32

typedef __attribute__((ext_vector_type(8))) short short8;
typedef __attribute__((ext_vector_type(4))) float floatx4;

__device__ inline ushort f2bf_rne(float f) {
    unsigned u = __float_as_uint(f);
    unsigned r = u + 0x7fffu + ((u >> 16) & 1u);
    return (ushort)(r >> 16);
}
__device__ inline float bf2f(ushort h) { return __uint_as_float(((unsigned)h) << 16); }

// W-array layout (ushort offsets), k-major [col][K] per segment:
//  gates l1 (1 chunk, ci=128): 0        size 32768
//  gates l2 (2 chunks, ci=64): 32768    each 16384
//  gates l3 (4 chunks, ci=128): 65536   each 32768
//  Wl1 [64][64]:               196608   size 4096
//  Wl2 (2 chunks) [128][64]:   200704   each 8192
//  total ushorts:              217088
#define WOFF_L2   32768
#define WOFF_L3   65536
#define WOFF_WL1  196608
#define WOFF_WL2  200704
#define W_TOTAL   217088

struct WSrc {
    const float* Wg[3][4];   // [layer][k,q,v,s]
    const float* Wl[2];      // layer1, layer2 (layer3's Wl handled in MLP)
    const float* bg[3][4];
};

__global__ void wconv(WSrc S, ushort* __restrict__ hi, ushort* __restrict__ lo,
                      float* __restrict__ biascat)
{
    int id = blockIdx.x * 256 + threadIdx.x;
    if (id < 196608) {
        int l, base, ci, co;
        if (id < 32768)      { l = 0; base = 0;        ci = 128; co = 64;  }
        else if (id < 65536) { l = 1; base = WOFF_L2;  ci = 64;  co = 128; }
        else                 { l = 2; base = WOFF_L3;  ci = 128; co = 256; }
        int r  = id - base;
        int g  = r / (co * ci);
        int r2 = r - g * co * ci;
        int c  = r2 / ci;
        int k  = r2 - c * ci;
        float v = S.Wg[l][g][k * co + c];
        int ch  = c >> 6;
        int dst = base + ch * (256 * ci) + (((g << 6) + (c & 63)) * ci) + k;
        ushort h = f2bf_rne(v);
        hi[dst] = h; lo[dst] = f2bf_rne(v - bf2f(h));
    } else if (id < 196608 + 4096) {
        int r = id - 196608;
        int c = r >> 6, k = r & 63;
        float v = S.Wl[0][k * 64 + c];
        int dst = WOFF_WL1 + c * 64 + k;
        ushort h = f2bf_rne(v);
        hi[dst] = h; lo[dst] = f2bf_rne(v - bf2f(h));
    } else if (id < W_TOTAL) {
        int r = id - WOFF_WL2;
        int ch = r >> 13, r2 = r & 8191;
        int c = r2 >> 6, k = r2 & 63;
        float v = S.Wl[1][(ch * 64 + k) * 128 + c];
        int dst = WOFF_WL2 + ch * 8192 + c * 64 + k;
        ushort h = f2bf_rne(v);
        hi[dst] = h; lo[dst] = f2bf_rne(v - bf2f(h));
    } else if (id < W_TOTAL + 1792) {
        int i = id - W_TOTAL;
        int chunk = i >> 8, c = i & 255;
        int g = c >> 6, cc = c & 63;
        const int ltab[7] = {0, 1, 1, 2, 2, 2, 2};
        const int ctab[7] = {0, 0, 64, 0, 64, 128, 192};
        biascat[i] = S.bg[ltab[chunk]][g][ctab[chunk] + cc];
    }
}

// C[N, BC*gridDim.y] (+)= act(A)[N,K] @ B[K, cols] (+ bias)
// B given as bf16 hi/lo, k-major [col][K]. 3 MFMAs per tile (hi*hi,hi*lo,lo*hi).
template<int BC>   // block col width: 128 or 64; block rows always 128
__global__ __launch_bounds__(256) void gemm_bf3(
    const float* __restrict__ A, int lda,
    const ushort* __restrict__ Bh, const ushort* __restrict__ Bl,
    const float* __restrict__ bias,
    float* __restrict__ C, int ldc,
    int K, int leaky, int accum)
{
    constexpr int RT = (BC == 128) ? 4 : 2;   // 16-row tiles per wave
    __shared__ ushort sAh[128][40], sAl[128][40];   // pad 32->40 (16B-aligned rows)
    __shared__ ushort sBh[BC][40],  sBl[BC][40];

    const int tid  = threadIdx.x;
    const int w    = tid >> 6, lane = tid & 63;
    const int m    = lane & 15, quad = lane >> 4;
    const int row0 = blockIdx.x * 128;
    const int col0 = blockIdx.y * BC;
    const int wr   = (BC == 128) ? (w >> 1) * 64 : w * 32;
    const int wc   = (BC == 128) ? (w & 1) * 64 : 0;

    floatx4 acc[RT][4];
    #pragma unroll
    for (int i = 0; i < RT; ++i)
        #pragma unroll
        for (int j = 0; j < 4; ++j) acc[i][j] = (floatx4){0.f, 0.f, 0.f, 0.f};

    const int ar = tid >> 1;            // A stage: row 0..127
    const int ak = (tid & 1) * 16;      // k-offset 0 or 16 (16 floats per thread)

    for (int k0 = 0; k0 < K; k0 += 32) {
        // ---- stage A (fp32 -> bf16 hi/lo) ----
        {
            float av[16];
            int arow = row0 + ar;
            if (arow < GN_N) {
                const float* ap = A + (size_t)arow * lda + k0 + ak;
                #pragma unroll
                for (int j = 0; j < 4; ++j) {
                    float4 t = *(const float4*)(ap + j * 4);
                    av[j*4+0] = t.x; av[j*4+1] = t.y; av[j*4+2] = t.z; av[j*4+3] = t.w;
                }
            } else {
                #pragma unroll
                for (int j = 0; j < 16; ++j) av[j] = 0.f;
            }
            if (leaky) {
                #pragma unroll
                for (int j = 0; j < 16; ++j) av[j] = av[j] > 0.f ? av[j] : 0.01f * av[j];
            }
            short8 h0, h1, l0, l1;
            #pragma unroll
            for (int j = 0; j < 8; ++j) {
                ushort h = f2bf_rne(av[j]);
                h0[j] = (short)h; l0[j] = (short)f2bf_rne(av[j] - bf2f(h));
            }
            #pragma unroll
            for (int j = 0; j < 8; ++j) {
                ushort h = f2bf_rne(av[8 + j]);
                h1[j] = (short)h; l1[j] = (short)f2bf_rne(av[8 + j] - bf2f(h));
            }
            *(short8*)&sAh[ar][ak]     = h0;  *(short8*)&sAh[ar][ak + 8] = h1;
            *(short8*)&sAl[ar][ak]     = l0;  *(short8*)&sAl[ar][ak + 8] = l1;
        }
        // ---- stage B (pre-converted, coalesced k-major) ----
        if (BC == 128) {
            int col = tid >> 1, bk = (tid & 1) * 16;
            size_t off = (size_t)(col0 + col) * K + k0 + bk;
            *(short8*)&sBh[col][bk]     = *(const short8*)(Bh + off);
            *(short8*)&sBh[col][bk + 8] = *(const short8*)(Bh + off + 8);
            *(short8*)&sBl[col][bk]     = *(const short8*)(Bl + off);
            *(short8*)&sBl[col][bk + 8] = *(const short8*)(Bl + off + 8);
        } else {
            int col = tid >> 2, bk = (tid & 3) * 8;
            size_t off = (size_t)(col0 + col) * K + k0 + bk;
            *(short8*)&sBh[col][bk] = *(const short8*)(Bh + off);
            *(short8*)&sBl[col][bk] = *(const short8*)(Bl + off);
        }
        __syncthreads();
        // ---- compute ----
        short8 bhf[4], blf[4];
        #pragma unroll
        for (int ct = 0; ct < 4; ++ct) {
            bhf[ct] = *(const short8*)&sBh[wc + ct * 16 + m][quad * 8];
            blf[ct] = *(const short8*)&sBl[wc + ct * 16 + m][quad * 8];
        }
        #pragma unroll
        for (int rt = 0; rt < RT; ++rt) {
            short8 ahf = *(const short8*)&sAh[wr + rt * 16 + m][quad * 8];
            short8 alf = *(const short8*)&sAl[wr + rt * 16 + m][quad * 8];
            #pragma unroll
            for (int ct = 0; ct < 4; ++ct) {
                acc[rt][ct] = __builtin_amdgcn_mfma_f32_16x16x32_bf16(ahf, bhf[ct], acc[rt][ct], 0, 0, 0);
                acc[rt][ct] = __builtin_amdgcn_mfma_f32_16x16x32_bf16(ahf, blf[ct], acc[rt][ct], 0, 0, 0);
                acc[rt][ct] = __builtin_amdgcn_mfma_f32_16x16x32_bf16(alf, bhf[ct], acc[rt][ct], 0, 0, 0);
            }
        }
        __syncthreads();
    }

    // ---- epilogue: D[row=quad*4+reg][col=lane&15] ----
    #pragma unroll
    for (int rt = 0; rt < RT; ++rt) {
        #pragma unroll
        for (int ct = 0; ct < 4; ++ct) {
            int ocol = col0 + wc + ct * 16 + m;
            #pragma unroll
            for (int reg = 0; reg < 4; ++reg) {
                int orow = row0 + wr + rt * 16 + quad * 4 + reg;
                if (orow < GN_N) {
                    float v = acc[rt][ct][reg];
                    if (accum) v += C[(size_t)orow * ldc + ocol];
                    else       v += bias[ocol];
                    C[(size_t)orow * ldc + ocol] = v;
                }
            }
        }
    }
}

// ---------------- CSR build ----------------
__global__ void zero_int(int* p, int n)
{
    int i = blockIdx.x * 256 + threadIdx.x;
    if (i < n) p[i] = 0;
}

__global__ void hist_kernel(const int* __restrict__ dst, int* __restrict__ deg)
{
    int e = blockIdx.x * 256 + threadIdx.x;
    if (e < GN_E) atomicAdd(&deg[dst[e]], 1);
}

__global__ void scan1(const int* __restrict__ deg, int* __restrict__ rp, int* __restrict__ bsums)
{
    __shared__ int s[256];
    int b = blockIdx.x, t = threadIdx.x;
    int i = b * 256 + t;
    int v = (i < GN_N) ? deg[i] : 0;
    s[t] = v;
    __syncthreads();
    for (int off = 1; off < 256; off <<= 1) {
        int x = (t >= off) ? s[t - off] : 0;
        __syncthreads();
        s[t] += x;
        __syncthreads();
    }
    if (i < GN_N) rp[i] = s[t] - v;
    if (t == 255) bsums[b] = s[255];
}

__global__ __launch_bounds__(512) void scan2(int* bsums, int nb)
{
    __shared__ int s[512];
    int t = threadIdx.x;
    int v = (t < nb) ? bsums[t] : 0;
    s[t] = v;
    __syncthreads();
    for (int off = 1; off < 512; off <<= 1) {
        int x = (t >= off) ? s[t - off] : 0;
        __syncthreads();
        s[t] += x;
        __syncthreads();
    }
    if (t < nb) bsums[t] = s[t] - v;
}

__global__ void scan3(const int* __restrict__ bsums, int* __restrict__ rp, int* __restrict__ cursor)
{
    int b = blockIdx.x, t = threadIdx.x;
    int i = b * 256 + t;
    if (i < GN_N) {
        int v = rp[i] + bsums[b];
        rp[i] = v; cursor[i] = v;
    }
    if (i == 0) rp[GN_N] = GN_E;
}

__global__ void scatter_kernel(
    const int* __restrict__ src, const int* __restrict__ dst,
    int* __restrict__ cursor, int* __restrict__ elist)
{
    int e = blockIdx.x * 256 + threadIdx.x;
    if (e >= GN_E) return;
    int d = dst[e];
    int pos = atomicAdd(&cursor[d], 1);
    elist[pos] = src[e];
}

// agg(S-section) = S + sum_{s->node} relu(K[node]+Q[s])*V[s], in-place on G.
__global__ __launch_bounds__(256) void edge_gather(
    float* __restrict__ G,
    const int* __restrict__ row_ptr, const int* __restrict__ elist)
{
    int node = blockIdx.x * 4 + (threadIdx.x >> 6);
    if (node >= GN_N) return;
    int c = threadIdx.x & 63;
    int beg = row_ptr[node], end = row_ptr[node + 1];
    float k   = G[(size_t)node * 256 + c];
    float acc = G[(size_t)node * 256 + 192 + c];
    for (int i = beg; i < end; ++i) {
        int s = elist[i];
        float q = G[(size_t)s * 256 + 64 + c];
        float v = G[(size_t)s * 256 + 128 + c];
        float g = k + q;
        if (g > 0.f) acc += g * v;
    }
    G[(size_t)node * 256 + 192 + c] = acc;
}

__global__ void zero_kernel(float* sums, float* cnt)
{
    int i = blockIdx.x * 256 + threadIdx.x;
    if (i < GN_G * 256) sums[i] = 0.0f;
    else if (i < GN_G * 256 + GN_G) cnt[i - GN_G * 256] = 0.0f;
}

// Pool leaky(S-section of G) into sums[:, c0:c0+64]. batch sorted ascending.
__global__ __launch_bounds__(64) void pool_chunk(
    const float* __restrict__ aggbase, const int* __restrict__ batch,
    float* __restrict__ sums, float* __restrict__ cnt, int c0, int do_cnt)
{
    int c = threadIdx.x;
    int start = blockIdx.x * 512;
    if (start >= GN_N) return;
    int end = min(start + 512, GN_N);
    float acc = 0.0f, n = 0.0f;
    int curg = batch[start];
    for (int node = start; node < end; ++node) {
        int g = batch[node];
        if (g != curg) {
            atomicAdd(&sums[curg * 256 + c0 + c], acc);
            if (do_cnt && c == 0) atomicAdd(&cnt[curg], n);
            acc = 0.0f; n = 0.0f; curg = g;
        }
        float v = aggbase[(size_t)node * 256 + c];
        v = v > 0.f ? v : 0.01f * v;
        acc += v; n += 1.0f;
    }
    atomicAdd(&sums[curg * 256 + c0 + c], acc);
    if (do_cnt && c == 0) atomicAdd(&cnt[curg], n);
}

// Single block: Pl = sums/cnt; Pg = Pl @ Wl3 + bl3; then BN-MLP chain.
__global__ __launch_bounds__(256) void mlp_kernel(
    const float* __restrict__ sums, const float* __restrict__ cnt,
    const float* __restrict__ Wl3, const float* __restrict__ bl3,
    const float* __restrict__ W1, const float* __restrict__ b1,
    const float* __restrict__ Wh, const float* __restrict__ bh,
    const float* __restrict__ Wo, const float* __restrict__ bo,
    const float* __restrict__ gamma, const float* __restrict__ beta,
    const float* __restrict__ mean, const float* __restrict__ var,
    float* __restrict__ out)
{
    __shared__ float buf[GN_G * 256];
    __shared__ float sh[2][GN_G * 64];
    int t = threadIdx.x;

    for (int i = t; i < GN_G * 256; i += 256) {
        int g = i >> 8;
        buf[i] = sums[i] / fmaxf(cnt[g], 1.0f);
    }
    __syncthreads();

    {
        float pg[GN_G];
        #pragma unroll 4
        for (int g = 0; g < GN_G; ++g) {
            float acc = bl3[t];
            for (int k = 0; k < 256; ++k)
                acc += buf[g * 256 + k] * Wl3[k * 256 + t];
            pg[g] = acc;
        }
        __syncthreads();
        for (int g = 0; g < GN_G; ++g) buf[g * 256 + t] = pg[g];
        __syncthreads();
    }

    for (int i = t; i < GN_G * 64; i += 256) {
        int g = i >> 6, c = i & 63;
        float acc = b1[c];
        for (int k = 0; k < 256; ++k) acc += buf[g * 256 + k] * W1[k * 64 + c];
        float sc = gamma[c] * rsqrtf(var[c] + 1e-5f);
        acc = (acc - mean[c]) * sc + beta[c];
        sh[0][i] = fmaxf(acc, 0.0f);
    }
    __syncthreads();

    int cur = 0;
    for (int L = 0; L < 3; ++L) {
        const float* W  = Wh + L * 64 * 64;
        const float* b  = bh + L * 64;
        const float* ga = gamma + (L + 1) * 64;
        const float* be = beta  + (L + 1) * 64;
        const float* me = mean  + (L + 1) * 64;
        const float* va = var   + (L + 1) * 64;
        for (int i = t; i < GN_G * 64; i += 256) {
            int g = i >> 6, c = i & 63;
            float acc = b[c];
            for (int k = 0; k < 64; ++k) acc += sh[cur][g * 64 + k] * W[k * 64 + c];
            float sc = ga[c] * rsqrtf(va[c] + 1e-5f);
            acc = (acc - me[c]) * sc + be[c];
            sh[1 - cur][i] = fmaxf(acc, 0.0f);
        }
        cur = 1 - cur;
        __syncthreads();
    }

    {
        int g = t >> 3, c = t & 7;
        float acc = bo[c];
        for (int k = 0; k < 64; ++k) acc += sh[cur][g * 64 + k] * Wo[k * 8 + c];
        out[g * 8 + c] = acc;
    }
}

extern "C" void kernel_launch(void* const* d_in, const int* in_sizes, int n_in,
                              void* d_out, int out_size, void* d_ws, size_t ws_size,
                              hipStream_t stream)
{
    const int N = GN_N, E = GN_E;
    const float* x          = (const float*)d_in[0];
    const int*   edge_index = (const int*)d_in[1];
    const int*   batch      = (const int*)d_in[2];
    const int*   src = edge_index;
    const int*   dst = edge_index + E;
    auto F = [&](int i) { return (const float*)d_in[i]; };

    // ---- workspace layout ----
    float* ws    = (float*)d_ws;
    float* G     = ws;                          // N x 256  [K|Q|V|S]
    float* hA    = G  + (size_t)N * 256;        // N x 64
    float* hB    = hA + (size_t)N * 64;         // N x 128
    float* sums  = hB + (size_t)N * 128;        // 32 x 256
    float* cnt   = sums + GN_G * 256;           // 32
    float* bcat  = cnt + GN_G;                  // 7 x 256
    ushort* Whi  = (ushort*)(bcat + 1792);      // W_TOTAL ushorts (16B-aligned)
    ushort* Wlo  = Whi + W_TOTAL;
    int* deg     = (int*)(Wlo + W_TOTAL);
    int* cursor  = deg + N;
    int* row_ptr = cursor + N;                  // N+1
    int* elist   = row_ptr + (N + 1);           // E
    int* bsums   = elist + E;                   // 512

    size_t need = (size_t)((char*)(bsums + 512) - (char*)ws);
    if (ws_size < need) return;

    // ---- CSR build ----
    const int eb = (E + 255) / 256;
    const int nb = (N + 255) / 256;   // 391
    zero_int<<<nb, 256, 0, stream>>>(deg, N);
    hist_kernel<<<eb, 256, 0, stream>>>(dst, deg);
    scan1<<<nb, 256, 0, stream>>>(deg, row_ptr, bsums);
    scan2<<<1, 512, 0, stream>>>(bsums, nb);
    scan3<<<nb, 256, 0, stream>>>(bsums, row_ptr, cursor);
    scatter_kernel<<<eb, 256, 0, stream>>>(src, dst, cursor, elist);

    // ---- weight pre-conversion ----
    WSrc S;
    for (int l = 0; l < 3; ++l) {
        int base = 3 + l * 10;
        for (int g = 0; g < 4; ++g) S.Wg[l][g] = F(base + g);
        for (int g = 0; g < 4; ++g) S.bg[l][g] = F(base + 4 + g);
    }
    S.Wl[0] = F(11); S.Wl[1] = F(21);
    wconv<<<(W_TOTAL + 1792 + 255) / 256, 256, 0, stream>>>(S, Whi, Wlo, bcat);

    zero_kernel<<<(GN_G * 256 + GN_G + 255) / 256, 256, 0, stream>>>(sums, cnt);

    // ---- layers ----
    const int rb = (N + 127) / 128;           // 782
    const int gatherBlocks = (N + 3) / 4;

    struct LCfg { const float* hin; int lda, K, nch; size_t goff, gstride; int bchunk; };
    LCfg L[3] = {
        { x,  128, 128, 1, 0,        0,     0 },
        { hA,  64,  64, 2, WOFF_L2,  16384, 1 },
        { hB, 128, 128, 4, WOFF_L3,  32768, 3 },
    };

    for (int l = 0; l < 3; ++l) {
        for (int ch = 0; ch < L[l].nch; ++ch) {
            size_t go = L[l].goff + (size_t)ch * L[l].gstride;
            gemm_bf3<128><<<dim3(rb, 2), 256, 0, stream>>>(
                L[l].hin, L[l].lda, Whi + go, Wlo + go,
                bcat + (size_t)(L[l].bchunk + ch) * 256, G, 256, L[l].K, 0, 0);

            edge_gather<<<gatherBlocks, 256, 0, stream>>>(G, row_ptr, elist);

            if (l == 0) {
                gemm_bf3<64><<<dim3(rb, 1), 256, 0, stream>>>(
                    G + 192, 256, Whi + WOFF_WL1, Wlo + WOFF_WL1,
                    F(12), hA, 64, 64, 1, 0);
            } else if (l == 1) {
                gemm_bf3<128><<<dim3(rb, 1), 256, 0, stream>>>(
                    G + 192, 256, Whi + WOFF_WL2 + (size_t)ch * 8192,
                    Wlo + WOFF_WL2 + (size_t)ch * 8192,
                    F(22), hB, 128, 64, 1, ch > 0);
            } else {
                pool_chunk<<<(N + 511) / 512, 64, 0, stream>>>(
                    G + 192, batch, sums, cnt, ch * 64, ch == 0);
            }
        }
    }

    mlp_kernel<<<1, 256, 0, stream>>>(sums, cnt, F(31), F(32),
                                      F(33), F(34), F(35), F(36), F(37), F(38),
                                      F(39), F(40), F(41), F(42),
                                      (float*)d_out);
}

// Round 5
// 1433.339 us; speedup vs baseline: 2.3484x; 1.2656x over previous
//
#include <hip/hip_runtime.h>
#include <hip/hip_bf16.h>

// ---------------------------------------------------------------------------
// QuadraticGNN: 3x ResGatedGraphConv (ReLU gate, LeakyReLU 0.01, linear Wl)
//               -> global mean pool (32 graphs) -> 5-layer MLP with BN.
// Round 4:
//   - Layer-3 pooling fused into edge gather (edge_gather_pool): register
//     aggregate -> leaky -> LDS block-reduce -> ~64 atomics/block into sums.
//     Kills 4x pool_chunk (612us, 2% occupancy) + agg write-back/re-read.
//   - cnt[] via sorted-batch boundary detection (no atomics).
//   - Rest as round 3 (MFMA bf16x3 GEMMs, CSR gather, hierarchical scan).
// ---------------------------------------------------------------------------

#define GN_N 100000
#define GN_E 300000
#define GN_G 32

typedef __attribute__((ext_vector_type(8))) short short8;
typedef __attribute__((ext_vector_type(4))) float floatx4;

__device__ inline ushort f2bf_rne(float f) {
    unsigned u = __float_as_uint(f);
    unsigned r = u + 0x7fffu + ((u >> 16) & 1u);
    return (ushort)(r >> 16);
}
__device__ inline float bf2f(ushort h) { return __uint_as_float(((unsigned)h) << 16); }

// W-array layout (ushort offsets), k-major [col][K] per segment.
#define WOFF_L2   32768
#define WOFF_L3   65536
#define WOFF_WL1  196608
#define WOFF_WL2  200704
#define W_TOTAL   217088

struct WSrc {
    const float* Wg[3][4];
    const float* Wl[2];
    const float* bg[3][4];
};

__global__ void wconv(WSrc S, ushort* __restrict__ hi, ushort* __restrict__ lo,
                      float* __restrict__ biascat)
{
    int id = blockIdx.x * 256 + threadIdx.x;
    if (id < 196608) {
        int l, base, ci, co;
        if (id < 32768)      { l = 0; base = 0;        ci = 128; co = 64;  }
        else if (id < 65536) { l = 1; base = WOFF_L2;  ci = 64;  co = 128; }
        else                 { l = 2; base = WOFF_L3;  ci = 128; co = 256; }
        int r  = id - base;
        int g  = r / (co * ci);
        int r2 = r - g * co * ci;
        int c  = r2 / ci;
        int k  = r2 - c * ci;
        float v = S.Wg[l][g][k * co + c];
        int ch  = c >> 6;
        int dst = base + ch * (256 * ci) + (((g << 6) + (c & 63)) * ci) + k;
        ushort h = f2bf_rne(v);
        hi[dst] = h; lo[dst] = f2bf_rne(v - bf2f(h));
    } else if (id < 196608 + 4096) {
        int r = id - 196608;
        int c = r >> 6, k = r & 63;
        float v = S.Wl[0][k * 64 + c];
        int dst = WOFF_WL1 + c * 64 + k;
        ushort h = f2bf_rne(v);
        hi[dst] = h; lo[dst] = f2bf_rne(v - bf2f(h));
    } else if (id < W_TOTAL) {
        int r = id - WOFF_WL2;
        int ch = r >> 13, r2 = r & 8191;
        int c = r2 >> 6, k = r2 & 63;
        float v = S.Wl[1][(ch * 64 + k) * 128 + c];
        int dst = WOFF_WL2 + ch * 8192 + c * 64 + k;
        ushort h = f2bf_rne(v);
        hi[dst] = h; lo[dst] = f2bf_rne(v - bf2f(h));
    } else if (id < W_TOTAL + 1792) {
        int i = id - W_TOTAL;
        int chunk = i >> 8, c = i & 255;
        int g = c >> 6, cc = c & 63;
        const int ltab[7] = {0, 1, 1, 2, 2, 2, 2};
        const int ctab[7] = {0, 0, 64, 0, 64, 128, 192};
        biascat[i] = S.bg[ltab[chunk]][g][ctab[chunk] + cc];
    }
}

// C[N, BC*gridDim.y] (+)= act(A)[N,K] @ B[K, cols] (+ bias)
template<int BC>
__global__ __launch_bounds__(256) void gemm_bf3(
    const float* __restrict__ A, int lda,
    const ushort* __restrict__ Bh, const ushort* __restrict__ Bl,
    const float* __restrict__ bias,
    float* __restrict__ C, int ldc,
    int K, int leaky, int accum)
{
    constexpr int RT = (BC == 128) ? 4 : 2;
    __shared__ ushort sAh[128][40], sAl[128][40];
    __shared__ ushort sBh[BC][40],  sBl[BC][40];

    const int tid  = threadIdx.x;
    const int w    = tid >> 6, lane = tid & 63;
    const int m    = lane & 15, quad = lane >> 4;
    const int row0 = blockIdx.x * 128;
    const int col0 = blockIdx.y * BC;
    const int wr   = (BC == 128) ? (w >> 1) * 64 : w * 32;
    const int wc   = (BC == 128) ? (w & 1) * 64 : 0;

    floatx4 acc[RT][4];
    #pragma unroll
    for (int i = 0; i < RT; ++i)
        #pragma unroll
        for (int j = 0; j < 4; ++j) acc[i][j] = (floatx4){0.f, 0.f, 0.f, 0.f};

    const int ar = tid >> 1;
    const int ak = (tid & 1) * 16;

    for (int k0 = 0; k0 < K; k0 += 32) {
        {
            float av[16];
            int arow = row0 + ar;
            if (arow < GN_N) {
                const float* ap = A + (size_t)arow * lda + k0 + ak;
                #pragma unroll
                for (int j = 0; j < 4; ++j) {
                    float4 t = *(const float4*)(ap + j * 4);
                    av[j*4+0] = t.x; av[j*4+1] = t.y; av[j*4+2] = t.z; av[j*4+3] = t.w;
                }
            } else {
                #pragma unroll
                for (int j = 0; j < 16; ++j) av[j] = 0.f;
            }
            if (leaky) {
                #pragma unroll
                for (int j = 0; j < 16; ++j) av[j] = av[j] > 0.f ? av[j] : 0.01f * av[j];
            }
            short8 h0, h1, l0, l1;
            #pragma unroll
            for (int j = 0; j < 8; ++j) {
                ushort h = f2bf_rne(av[j]);
                h0[j] = (short)h; l0[j] = (short)f2bf_rne(av[j] - bf2f(h));
            }
            #pragma unroll
            for (int j = 0; j < 8; ++j) {
                ushort h = f2bf_rne(av[8 + j]);
                h1[j] = (short)h; l1[j] = (short)f2bf_rne(av[8 + j] - bf2f(h));
            }
            *(short8*)&sAh[ar][ak]     = h0;  *(short8*)&sAh[ar][ak + 8] = h1;
            *(short8*)&sAl[ar][ak]     = l0;  *(short8*)&sAl[ar][ak + 8] = l1;
        }
        if (BC == 128) {
            int col = tid >> 1, bk = (tid & 1) * 16;
            size_t off = (size_t)(col0 + col) * K + k0 + bk;
            *(short8*)&sBh[col][bk]     = *(const short8*)(Bh + off);
            *(short8*)&sBh[col][bk + 8] = *(const short8*)(Bh + off + 8);
            *(short8*)&sBl[col][bk]     = *(const short8*)(Bl + off);
            *(short8*)&sBl[col][bk + 8] = *(const short8*)(Bl + off + 8);
        } else {
            int col = tid >> 2, bk = (tid & 3) * 8;
            size_t off = (size_t)(col0 + col) * K + k0 + bk;
            *(short8*)&sBh[col][bk] = *(const short8*)(Bh + off);
            *(short8*)&sBl[col][bk] = *(const short8*)(Bl + off);
        }
        __syncthreads();
        short8 bhf[4], blf[4];
        #pragma unroll
        for (int ct = 0; ct < 4; ++ct) {
            bhf[ct] = *(const short8*)&sBh[wc + ct * 16 + m][quad * 8];
            blf[ct] = *(const short8*)&sBl[wc + ct * 16 + m][quad * 8];
        }
        #pragma unroll
        for (int rt = 0; rt < RT; ++rt) {
            short8 ahf = *(const short8*)&sAh[wr + rt * 16 + m][quad * 8];
            short8 alf = *(const short8*)&sAl[wr + rt * 16 + m][quad * 8];
            #pragma unroll
            for (int ct = 0; ct < 4; ++ct) {
                acc[rt][ct] = __builtin_amdgcn_mfma_f32_16x16x32_bf16(ahf, bhf[ct], acc[rt][ct], 0, 0, 0);
                acc[rt][ct] = __builtin_amdgcn_mfma_f32_16x16x32_bf16(ahf, blf[ct], acc[rt][ct], 0, 0, 0);
                acc[rt][ct] = __builtin_amdgcn_mfma_f32_16x16x32_bf16(alf, bhf[ct], acc[rt][ct], 0, 0, 0);
            }
        }
        __syncthreads();
    }

    #pragma unroll
    for (int rt = 0; rt < RT; ++rt) {
        #pragma unroll
        for (int ct = 0; ct < 4; ++ct) {
            int ocol = col0 + wc + ct * 16 + m;
            #pragma unroll
            for (int reg = 0; reg < 4; ++reg) {
                int orow = row0 + wr + rt * 16 + quad * 4 + reg;
                if (orow < GN_N) {
                    float v = acc[rt][ct][reg];
                    if (accum) v += C[(size_t)orow * ldc + ocol];
                    else       v += bias[ocol];
                    C[(size_t)orow * ldc + ocol] = v;
                }
            }
        }
    }
}

// ---------------- CSR build ----------------
__global__ void zero_int(int* p, int n)
{
    int i = blockIdx.x * 256 + threadIdx.x;
    if (i < n) p[i] = 0;
}

__global__ void hist_kernel(const int* __restrict__ dst, int* __restrict__ deg)
{
    int e = blockIdx.x * 256 + threadIdx.x;
    if (e < GN_E) atomicAdd(&deg[dst[e]], 1);
}

__global__ void scan1(const int* __restrict__ deg, int* __restrict__ rp, int* __restrict__ bsums)
{
    __shared__ int s[256];
    int b = blockIdx.x, t = threadIdx.x;
    int i = b * 256 + t;
    int v = (i < GN_N) ? deg[i] : 0;
    s[t] = v;
    __syncthreads();
    for (int off = 1; off < 256; off <<= 1) {
        int x = (t >= off) ? s[t - off] : 0;
        __syncthreads();
        s[t] += x;
        __syncthreads();
    }
    if (i < GN_N) rp[i] = s[t] - v;
    if (t == 255) bsums[b] = s[255];
}

__global__ __launch_bounds__(512) void scan2(int* bsums, int nb)
{
    __shared__ int s[512];
    int t = threadIdx.x;
    int v = (t < nb) ? bsums[t] : 0;
    s[t] = v;
    __syncthreads();
    for (int off = 1; off < 512; off <<= 1) {
        int x = (t >= off) ? s[t - off] : 0;
        __syncthreads();
        s[t] += x;
        __syncthreads();
    }
    if (t < nb) bsums[t] = s[t] - v;
}

__global__ void scan3(const int* __restrict__ bsums, int* __restrict__ rp, int* __restrict__ cursor)
{
    int b = blockIdx.x, t = threadIdx.x;
    int i = b * 256 + t;
    if (i < GN_N) {
        int v = rp[i] + bsums[b];
        rp[i] = v; cursor[i] = v;
    }
    if (i == 0) rp[GN_N] = GN_E;
}

__global__ void scatter_kernel(
    const int* __restrict__ src, const int* __restrict__ dst,
    int* __restrict__ cursor, int* __restrict__ elist)
{
    int e = blockIdx.x * 256 + threadIdx.x;
    if (e >= GN_E) return;
    int d = dst[e];
    int pos = atomicAdd(&cursor[d], 1);
    elist[pos] = src[e];
}

// Graph segment boundaries on sorted batch -> se[0..31]=start, se[32..63]=end.
__global__ void bounds_kernel(const int* __restrict__ batch, int* __restrict__ se)
{
    int i = blockIdx.x * 256 + threadIdx.x;
    if (i >= GN_N) return;
    int g = batch[i];
    if (i == 0 || batch[i - 1] != g) se[g] = i;
    if (i == GN_N - 1 || batch[i + 1] != g) se[32 + g] = i + 1;
}

__global__ void cnt_kernel(const int* __restrict__ se, float* __restrict__ cnt)
{
    int g = threadIdx.x;
    if (g < GN_G) cnt[g] = (float)(se[32 + g] - se[g]);
}

// agg(S-section) = S + sum_{s->node} relu(K[node]+Q[s])*V[s], in-place on G.
__global__ __launch_bounds__(256) void edge_gather(
    float* __restrict__ G,
    const int* __restrict__ row_ptr, const int* __restrict__ elist)
{
    int node = blockIdx.x * 4 + (threadIdx.x >> 6);
    if (node >= GN_N) return;
    int c = threadIdx.x & 63;
    int beg = row_ptr[node], end = row_ptr[node + 1];
    float k   = G[(size_t)node * 256 + c];
    float acc = G[(size_t)node * 256 + 192 + c];
    for (int i = beg; i < end; ++i) {
        int s = elist[i];
        float q = G[(size_t)s * 256 + 64 + c];
        float v = G[(size_t)s * 256 + 128 + c];
        float g = k + q;
        if (g > 0.f) acc += g * v;
    }
    G[(size_t)node * 256 + 192 + c] = acc;
}

// Layer-3: edge gather + leaky + block-reduced mean-pool accumulate. No G write.
__global__ __launch_bounds__(256) void edge_gather_pool(
    const float* __restrict__ G,
    const int* __restrict__ row_ptr, const int* __restrict__ elist,
    const int* __restrict__ batch,
    float* __restrict__ sums, int c0)
{
    __shared__ float red[4][64];
    __shared__ int gid[4];
    int w = threadIdx.x >> 6, c = threadIdx.x & 63;
    int node = blockIdx.x * 4 + w;
    float acc = 0.f;
    int g = -1;
    if (node < GN_N) {
        g = batch[node];
        int beg = row_ptr[node], end = row_ptr[node + 1];
        float k = G[(size_t)node * 256 + c];
        acc = G[(size_t)node * 256 + 192 + c];
        for (int i = beg; i < end; ++i) {
            int s = elist[i];
            float q = G[(size_t)s * 256 + 64 + c];
            float v = G[(size_t)s * 256 + 128 + c];
            float gt = k + q;
            if (gt > 0.f) acc += gt * v;
        }
        acc = acc > 0.f ? acc : 0.01f * acc;   // leaky
    }
    red[w][c] = acc;
    if (c == 0) gid[w] = g;
    __syncthreads();
    if (w == 0) {
        int i = 0;
        while (i < 4) {           // run-length combine (sorted batch => few runs)
            int gg = gid[i];
            float s = 0.f;
            int j = i;
            while (j < 4 && gid[j] == gg) { s += red[j][c]; ++j; }
            if (gg >= 0) atomicAdd(&sums[gg * 256 + c0 + c], s);
            i = j;
        }
    }
}

__global__ void zero_sums(float* sums)
{
    int i = blockIdx.x * 256 + threadIdx.x;
    if (i < GN_G * 256) sums[i] = 0.0f;
}

// Single block: Pl = sums/cnt; Pg = Pl @ Wl3 + bl3; then BN-MLP chain.
__global__ __launch_bounds__(256) void mlp_kernel(
    const float* __restrict__ sums, const float* __restrict__ cnt,
    const float* __restrict__ Wl3, const float* __restrict__ bl3,
    const float* __restrict__ W1, const float* __restrict__ b1,
    const float* __restrict__ Wh, const float* __restrict__ bh,
    const float* __restrict__ Wo, const float* __restrict__ bo,
    const float* __restrict__ gamma, const float* __restrict__ beta,
    const float* __restrict__ mean, const float* __restrict__ var,
    float* __restrict__ out)
{
    __shared__ float buf[GN_G * 256];
    __shared__ float sh[2][GN_G * 64];
    int t = threadIdx.x;

    for (int i = t; i < GN_G * 256; i += 256) {
        int g = i >> 8;
        buf[i] = sums[i] / fmaxf(cnt[g], 1.0f);
    }
    __syncthreads();

    {
        float pg[GN_G];
        #pragma unroll 4
        for (int g = 0; g < GN_G; ++g) {
            float acc = bl3[t];
            for (int k = 0; k < 256; ++k)
                acc += buf[g * 256 + k] * Wl3[k * 256 + t];
            pg[g] = acc;
        }
        __syncthreads();
        for (int g = 0; g < GN_G; ++g) buf[g * 256 + t] = pg[g];
        __syncthreads();
    }

    for (int i = t; i < GN_G * 64; i += 256) {
        int g = i >> 6, c = i & 63;
        float acc = b1[c];
        for (int k = 0; k < 256; ++k) acc += buf[g * 256 + k] * W1[k * 64 + c];
        float sc = gamma[c] * rsqrtf(var[c] + 1e-5f);
        acc = (acc - mean[c]) * sc + beta[c];
        sh[0][i] = fmaxf(acc, 0.0f);
    }
    __syncthreads();

    int cur = 0;
    for (int L = 0; L < 3; ++L) {
        const float* W  = Wh + L * 64 * 64;
        const float* b  = bh + L * 64;
        const float* ga = gamma + (L + 1) * 64;
        const float* be = beta  + (L + 1) * 64;
        const float* me = mean  + (L + 1) * 64;
        const float* va = var   + (L + 1) * 64;
        for (int i = t; i < GN_G * 64; i += 256) {
            int g = i >> 6, c = i & 63;
            float acc = b[c];
            for (int k = 0; k < 64; ++k) acc += sh[cur][g * 64 + k] * W[k * 64 + c];
            float sc = ga[c] * rsqrtf(va[c] + 1e-5f);
            acc = (acc - me[c]) * sc + be[c];
            sh[1 - cur][i] = fmaxf(acc, 0.0f);
        }
        cur = 1 - cur;
        __syncthreads();
    }

    {
        int g = t >> 3, c = t & 7;
        float acc = bo[c];
        for (int k = 0; k < 64; ++k) acc += sh[cur][g * 64 + k] * Wo[k * 8 + c];
        out[g * 8 + c] = acc;
    }
}

extern "C" void kernel_launch(void* const* d_in, const int* in_sizes, int n_in,
                              void* d_out, int out_size, void* d_ws, size_t ws_size,
                              hipStream_t stream)
{
    const int N = GN_N, E = GN_E;
    const float* x          = (const float*)d_in[0];
    const int*   edge_index = (const int*)d_in[1];
    const int*   batch      = (const int*)d_in[2];
    const int*   src = edge_index;
    const int*   dst = edge_index + E;
    auto F = [&](int i) { return (const float*)d_in[i]; };

    // ---- workspace layout ----
    float* ws    = (float*)d_ws;
    float* G     = ws;                          // N x 256  [K|Q|V|S]
    float* hA    = G  + (size_t)N * 256;        // N x 64
    float* hB    = hA + (size_t)N * 64;         // N x 128
    float* sums  = hB + (size_t)N * 128;        // 32 x 256
    float* cnt   = sums + GN_G * 256;           // 32
    float* bcat  = cnt + GN_G;                  // 7 x 256
    ushort* Whi  = (ushort*)(bcat + 1792);
    ushort* Wlo  = Whi + W_TOTAL;
    int* deg     = (int*)(Wlo + W_TOTAL);
    int* cursor  = deg + N;
    int* row_ptr = cursor + N;                  // N+1
    int* elist   = row_ptr + (N + 1);           // E
    int* bsums   = elist + E;                   // 512
    int* se      = bsums + 512;                 // 64

    size_t need = (size_t)((char*)(se + 64) - (char*)ws);
    if (ws_size < need) return;

    // ---- CSR build + graph bounds ----
    const int eb = (E + 255) / 256;
    const int nb = (N + 255) / 256;
    zero_int<<<nb, 256, 0, stream>>>(deg, N);
    zero_int<<<1, 256, 0, stream>>>(se, 64);
    hist_kernel<<<eb, 256, 0, stream>>>(dst, deg);
    scan1<<<nb, 256, 0, stream>>>(deg, row_ptr, bsums);
    scan2<<<1, 512, 0, stream>>>(bsums, nb);
    scan3<<<nb, 256, 0, stream>>>(bsums, row_ptr, cursor);
    scatter_kernel<<<eb, 256, 0, stream>>>(src, dst, cursor, elist);
    bounds_kernel<<<nb, 256, 0, stream>>>(batch, se);
    cnt_kernel<<<1, 64, 0, stream>>>(se, cnt);

    // ---- weight pre-conversion ----
    WSrc S;
    for (int l = 0; l < 3; ++l) {
        int base = 3 + l * 10;
        for (int g = 0; g < 4; ++g) S.Wg[l][g] = F(base + g);
        for (int g = 0; g < 4; ++g) S.bg[l][g] = F(base + 4 + g);
    }
    S.Wl[0] = F(11); S.Wl[1] = F(21);
    wconv<<<(W_TOTAL + 1792 + 255) / 256, 256, 0, stream>>>(S, Whi, Wlo, bcat);

    zero_sums<<<(GN_G * 256 + 255) / 256, 256, 0, stream>>>(sums);

    // ---- layers ----
    const int rb = (N + 127) / 128;
    const int gatherBlocks = (N + 3) / 4;

    struct LCfg { const float* hin; int lda, K, nch; size_t goff, gstride; int bchunk; };
    LCfg L[3] = {
        { x,  128, 128, 1, 0,        0,     0 },
        { hA,  64,  64, 2, WOFF_L2,  16384, 1 },
        { hB, 128, 128, 4, WOFF_L3,  32768, 3 },
    };

    for (int l = 0; l < 3; ++l) {
        for (int ch = 0; ch < L[l].nch; ++ch) {
            size_t go = L[l].goff + (size_t)ch * L[l].gstride;
            gemm_bf3<128><<<dim3(rb, 2), 256, 0, stream>>>(
                L[l].hin, L[l].lda, Whi + go, Wlo + go,
                bcat + (size_t)(L[l].bchunk + ch) * 256, G, 256, L[l].K, 0, 0);

            if (l == 0) {
                edge_gather<<<gatherBlocks, 256, 0, stream>>>(G, row_ptr, elist);
                gemm_bf3<64><<<dim3(rb, 1), 256, 0, stream>>>(
                    G + 192, 256, Whi + WOFF_WL1, Wlo + WOFF_WL1,
                    F(12), hA, 64, 64, 1, 0);
            } else if (l == 1) {
                edge_gather<<<gatherBlocks, 256, 0, stream>>>(G, row_ptr, elist);
                gemm_bf3<128><<<dim3(rb, 1), 256, 0, stream>>>(
                    G + 192, 256, Whi + WOFF_WL2 + (size_t)ch * 8192,
                    Wlo + WOFF_WL2 + (size_t)ch * 8192,
                    F(22), hB, 128, 64, 1, ch > 0);
            } else {
                edge_gather_pool<<<gatherBlocks, 256, 0, stream>>>(
                    G, row_ptr, elist, batch, sums, ch * 64);
            }
        }
    }

    mlp_kernel<<<1, 256, 0, stream>>>(sums, cnt, F(31), F(32),
                                      F(33), F(34), F(35), F(36), F(37), F(38),
                                      F(39), F(40), F(41), F(42),
                                      (float*)d_out);
}

// Round 6
// 1305.901 us; speedup vs baseline: 2.5775x; 1.0976x over previous
//
#include <hip/hip_runtime.h>
#include <hip/hip_bf16.h>

// ---------------------------------------------------------------------------
// QuadraticGNN: 3x ResGatedGraphConv (ReLU gate, LeakyReLU 0.01, linear Wl)
//               -> global mean pool (32 graphs) -> 5-layer MLP with BN.
// Round 5:
//   - MLP parallelized: one block per graph (32 blocks). The old single-block
//     version was 148us at 0.046% occupancy (8192-FMA serial chains).
//   - Rest as round 4 (MFMA bf16x3 GEMMs, CSR gather, fused layer-3 pool).
// ---------------------------------------------------------------------------

#define GN_N 100000
#define GN_E 300000
#define GN_G 32

typedef __attribute__((ext_vector_type(8))) short short8;
typedef __attribute__((ext_vector_type(4))) float floatx4;

__device__ inline ushort f2bf_rne(float f) {
    unsigned u = __float_as_uint(f);
    unsigned r = u + 0x7fffu + ((u >> 16) & 1u);
    return (ushort)(r >> 16);
}
__device__ inline float bf2f(ushort h) { return __uint_as_float(((unsigned)h) << 16); }

// W-array layout (ushort offsets), k-major [col][K] per segment.
#define WOFF_L2   32768
#define WOFF_L3   65536
#define WOFF_WL1  196608
#define WOFF_WL2  200704
#define W_TOTAL   217088

struct WSrc {
    const float* Wg[3][4];
    const float* Wl[2];
    const float* bg[3][4];
};

__global__ void wconv(WSrc S, ushort* __restrict__ hi, ushort* __restrict__ lo,
                      float* __restrict__ biascat)
{
    int id = blockIdx.x * 256 + threadIdx.x;
    if (id < 196608) {
        int l, base, ci, co;
        if (id < 32768)      { l = 0; base = 0;        ci = 128; co = 64;  }
        else if (id < 65536) { l = 1; base = WOFF_L2;  ci = 64;  co = 128; }
        else                 { l = 2; base = WOFF_L3;  ci = 128; co = 256; }
        int r  = id - base;
        int g  = r / (co * ci);
        int r2 = r - g * co * ci;
        int c  = r2 / ci;
        int k  = r2 - c * ci;
        float v = S.Wg[l][g][k * co + c];
        int ch  = c >> 6;
        int dst = base + ch * (256 * ci) + (((g << 6) + (c & 63)) * ci) + k;
        ushort h = f2bf_rne(v);
        hi[dst] = h; lo[dst] = f2bf_rne(v - bf2f(h));
    } else if (id < 196608 + 4096) {
        int r = id - 196608;
        int c = r >> 6, k = r & 63;
        float v = S.Wl[0][k * 64 + c];
        int dst = WOFF_WL1 + c * 64 + k;
        ushort h = f2bf_rne(v);
        hi[dst] = h; lo[dst] = f2bf_rne(v - bf2f(h));
    } else if (id < W_TOTAL) {
        int r = id - WOFF_WL2;
        int ch = r >> 13, r2 = r & 8191;
        int c = r2 >> 6, k = r2 & 63;
        float v = S.Wl[1][(ch * 64 + k) * 128 + c];
        int dst = WOFF_WL2 + ch * 8192 + c * 64 + k;
        ushort h = f2bf_rne(v);
        hi[dst] = h; lo[dst] = f2bf_rne(v - bf2f(h));
    } else if (id < W_TOTAL + 1792) {
        int i = id - W_TOTAL;
        int chunk = i >> 8, c = i & 255;
        int g = c >> 6, cc = c & 63;
        const int ltab[7] = {0, 1, 1, 2, 2, 2, 2};
        const int ctab[7] = {0, 0, 64, 0, 64, 128, 192};
        biascat[i] = S.bg[ltab[chunk]][g][ctab[chunk] + cc];
    }
}

// C[N, BC*gridDim.y] (+)= act(A)[N,K] @ B[K, cols] (+ bias)
template<int BC>
__global__ __launch_bounds__(256) void gemm_bf3(
    const float* __restrict__ A, int lda,
    const ushort* __restrict__ Bh, const ushort* __restrict__ Bl,
    const float* __restrict__ bias,
    float* __restrict__ C, int ldc,
    int K, int leaky, int accum)
{
    constexpr int RT = (BC == 128) ? 4 : 2;
    __shared__ ushort sAh[128][40], sAl[128][40];
    __shared__ ushort sBh[BC][40],  sBl[BC][40];

    const int tid  = threadIdx.x;
    const int w    = tid >> 6, lane = tid & 63;
    const int m    = lane & 15, quad = lane >> 4;
    const int row0 = blockIdx.x * 128;
    const int col0 = blockIdx.y * BC;
    const int wr   = (BC == 128) ? (w >> 1) * 64 : w * 32;
    const int wc   = (BC == 128) ? (w & 1) * 64 : 0;

    floatx4 acc[RT][4];
    #pragma unroll
    for (int i = 0; i < RT; ++i)
        #pragma unroll
        for (int j = 0; j < 4; ++j) acc[i][j] = (floatx4){0.f, 0.f, 0.f, 0.f};

    const int ar = tid >> 1;
    const int ak = (tid & 1) * 16;

    for (int k0 = 0; k0 < K; k0 += 32) {
        {
            float av[16];
            int arow = row0 + ar;
            if (arow < GN_N) {
                const float* ap = A + (size_t)arow * lda + k0 + ak;
                #pragma unroll
                for (int j = 0; j < 4; ++j) {
                    float4 t = *(const float4*)(ap + j * 4);
                    av[j*4+0] = t.x; av[j*4+1] = t.y; av[j*4+2] = t.z; av[j*4+3] = t.w;
                }
            } else {
                #pragma unroll
                for (int j = 0; j < 16; ++j) av[j] = 0.f;
            }
            if (leaky) {
                #pragma unroll
                for (int j = 0; j < 16; ++j) av[j] = av[j] > 0.f ? av[j] : 0.01f * av[j];
            }
            short8 h0, h1, l0, l1;
            #pragma unroll
            for (int j = 0; j < 8; ++j) {
                ushort h = f2bf_rne(av[j]);
                h0[j] = (short)h; l0[j] = (short)f2bf_rne(av[j] - bf2f(h));
            }
            #pragma unroll
            for (int j = 0; j < 8; ++j) {
                ushort h = f2bf_rne(av[8 + j]);
                h1[j] = (short)h; l1[j] = (short)f2bf_rne(av[8 + j] - bf2f(h));
            }
            *(short8*)&sAh[ar][ak]     = h0;  *(short8*)&sAh[ar][ak + 8] = h1;
            *(short8*)&sAl[ar][ak]     = l0;  *(short8*)&sAl[ar][ak + 8] = l1;
        }
        if (BC == 128) {
            int col = tid >> 1, bk = (tid & 1) * 16;
            size_t off = (size_t)(col0 + col) * K + k0 + bk;
            *(short8*)&sBh[col][bk]     = *(const short8*)(Bh + off);
            *(short8*)&sBh[col][bk + 8] = *(const short8*)(Bh + off + 8);
            *(short8*)&sBl[col][bk]     = *(const short8*)(Bl + off);
            *(short8*)&sBl[col][bk + 8] = *(const short8*)(Bl + off + 8);
        } else {
            int col = tid >> 2, bk = (tid & 3) * 8;
            size_t off = (size_t)(col0 + col) * K + k0 + bk;
            *(short8*)&sBh[col][bk] = *(const short8*)(Bh + off);
            *(short8*)&sBl[col][bk] = *(const short8*)(Bl + off);
        }
        __syncthreads();
        short8 bhf[4], blf[4];
        #pragma unroll
        for (int ct = 0; ct < 4; ++ct) {
            bhf[ct] = *(const short8*)&sBh[wc + ct * 16 + m][quad * 8];
            blf[ct] = *(const short8*)&sBl[wc + ct * 16 + m][quad * 8];
        }
        #pragma unroll
        for (int rt = 0; rt < RT; ++rt) {
            short8 ahf = *(const short8*)&sAh[wr + rt * 16 + m][quad * 8];
            short8 alf = *(const short8*)&sAl[wr + rt * 16 + m][quad * 8];
            #pragma unroll
            for (int ct = 0; ct < 4; ++ct) {
                acc[rt][ct] = __builtin_amdgcn_mfma_f32_16x16x32_bf16(ahf, bhf[ct], acc[rt][ct], 0, 0, 0);
                acc[rt][ct] = __builtin_amdgcn_mfma_f32_16x16x32_bf16(ahf, blf[ct], acc[rt][ct], 0, 0, 0);
                acc[rt][ct] = __builtin_amdgcn_mfma_f32_16x16x32_bf16(alf, bhf[ct], acc[rt][ct], 0, 0, 0);
            }
        }
        __syncthreads();
    }

    #pragma unroll
    for (int rt = 0; rt < RT; ++rt) {
        #pragma unroll
        for (int ct = 0; ct < 4; ++ct) {
            int ocol = col0 + wc + ct * 16 + m;
            #pragma unroll
            for (int reg = 0; reg < 4; ++reg) {
                int orow = row0 + wr + rt * 16 + quad * 4 + reg;
                if (orow < GN_N) {
                    float v = acc[rt][ct][reg];
                    if (accum) v += C[(size_t)orow * ldc + ocol];
                    else       v += bias[ocol];
                    C[(size_t)orow * ldc + ocol] = v;
                }
            }
        }
    }
}

// ---------------- CSR build ----------------
__global__ void zero_int(int* p, int n)
{
    int i = blockIdx.x * 256 + threadIdx.x;
    if (i < n) p[i] = 0;
}

__global__ void hist_kernel(const int* __restrict__ dst, int* __restrict__ deg)
{
    int e = blockIdx.x * 256 + threadIdx.x;
    if (e < GN_E) atomicAdd(&deg[dst[e]], 1);
}

__global__ void scan1(const int* __restrict__ deg, int* __restrict__ rp, int* __restrict__ bsums)
{
    __shared__ int s[256];
    int b = blockIdx.x, t = threadIdx.x;
    int i = b * 256 + t;
    int v = (i < GN_N) ? deg[i] : 0;
    s[t] = v;
    __syncthreads();
    for (int off = 1; off < 256; off <<= 1) {
        int x = (t >= off) ? s[t - off] : 0;
        __syncthreads();
        s[t] += x;
        __syncthreads();
    }
    if (i < GN_N) rp[i] = s[t] - v;
    if (t == 255) bsums[b] = s[255];
}

__global__ __launch_bounds__(512) void scan2(int* bsums, int nb)
{
    __shared__ int s[512];
    int t = threadIdx.x;
    int v = (t < nb) ? bsums[t] : 0;
    s[t] = v;
    __syncthreads();
    for (int off = 1; off < 512; off <<= 1) {
        int x = (t >= off) ? s[t - off] : 0;
        __syncthreads();
        s[t] += x;
        __syncthreads();
    }
    if (t < nb) bsums[t] = s[t] - v;
}

__global__ void scan3(const int* __restrict__ bsums, int* __restrict__ rp, int* __restrict__ cursor)
{
    int b = blockIdx.x, t = threadIdx.x;
    int i = b * 256 + t;
    if (i < GN_N) {
        int v = rp[i] + bsums[b];
        rp[i] = v; cursor[i] = v;
    }
    if (i == 0) rp[GN_N] = GN_E;
}

__global__ void scatter_kernel(
    const int* __restrict__ src, const int* __restrict__ dst,
    int* __restrict__ cursor, int* __restrict__ elist)
{
    int e = blockIdx.x * 256 + threadIdx.x;
    if (e >= GN_E) return;
    int d = dst[e];
    int pos = atomicAdd(&cursor[d], 1);
    elist[pos] = src[e];
}

// Graph segment boundaries on sorted batch -> se[0..31]=start, se[32..63]=end.
__global__ void bounds_kernel(const int* __restrict__ batch, int* __restrict__ se)
{
    int i = blockIdx.x * 256 + threadIdx.x;
    if (i >= GN_N) return;
    int g = batch[i];
    if (i == 0 || batch[i - 1] != g) se[g] = i;
    if (i == GN_N - 1 || batch[i + 1] != g) se[32 + g] = i + 1;
}

__global__ void cnt_kernel(const int* __restrict__ se, float* __restrict__ cnt)
{
    int g = threadIdx.x;
    if (g < GN_G) cnt[g] = (float)(se[32 + g] - se[g]);
}

// agg(S-section) = S + sum_{s->node} relu(K[node]+Q[s])*V[s], in-place on G.
__global__ __launch_bounds__(256) void edge_gather(
    float* __restrict__ G,
    const int* __restrict__ row_ptr, const int* __restrict__ elist)
{
    int node = blockIdx.x * 4 + (threadIdx.x >> 6);
    if (node >= GN_N) return;
    int c = threadIdx.x & 63;
    int beg = row_ptr[node], end = row_ptr[node + 1];
    float k   = G[(size_t)node * 256 + c];
    float acc = G[(size_t)node * 256 + 192 + c];
    for (int i = beg; i < end; ++i) {
        int s = elist[i];
        float q = G[(size_t)s * 256 + 64 + c];
        float v = G[(size_t)s * 256 + 128 + c];
        float g = k + q;
        if (g > 0.f) acc += g * v;
    }
    G[(size_t)node * 256 + 192 + c] = acc;
}

// Layer-3: edge gather + leaky + block-reduced mean-pool accumulate. No G write.
__global__ __launch_bounds__(256) void edge_gather_pool(
    const float* __restrict__ G,
    const int* __restrict__ row_ptr, const int* __restrict__ elist,
    const int* __restrict__ batch,
    float* __restrict__ sums, int c0)
{
    __shared__ float red[4][64];
    __shared__ int gid[4];
    int w = threadIdx.x >> 6, c = threadIdx.x & 63;
    int node = blockIdx.x * 4 + w;
    float acc = 0.f;
    int g = -1;
    if (node < GN_N) {
        g = batch[node];
        int beg = row_ptr[node], end = row_ptr[node + 1];
        float k = G[(size_t)node * 256 + c];
        acc = G[(size_t)node * 256 + 192 + c];
        for (int i = beg; i < end; ++i) {
            int s = elist[i];
            float q = G[(size_t)s * 256 + 64 + c];
            float v = G[(size_t)s * 256 + 128 + c];
            float gt = k + q;
            if (gt > 0.f) acc += gt * v;
        }
        acc = acc > 0.f ? acc : 0.01f * acc;   // leaky
    }
    red[w][c] = acc;
    if (c == 0) gid[w] = g;
    __syncthreads();
    if (w == 0) {
        int i = 0;
        while (i < 4) {
            int gg = gid[i];
            float s = 0.f;
            int j = i;
            while (j < 4 && gid[j] == gg) { s += red[j][c]; ++j; }
            if (gg >= 0) atomicAdd(&sums[gg * 256 + c0 + c], s);
            i = j;
        }
    }
}

__global__ void zero_sums(float* sums)
{
    int i = blockIdx.x * 256 + threadIdx.x;
    if (i < GN_G * 256) sums[i] = 0.0f;
}

// One block per graph: Pl = sums[g]/cnt[g]; Pg = Pl @ Wl3 + bl3; BN-MLP chain.
__global__ __launch_bounds__(256) void mlp_kernel(
    const float* __restrict__ sums, const float* __restrict__ cnt,
    const float* __restrict__ Wl3, const float* __restrict__ bl3,
    const float* __restrict__ W1, const float* __restrict__ b1,
    const float* __restrict__ Wh, const float* __restrict__ bh,
    const float* __restrict__ Wo, const float* __restrict__ bo,
    const float* __restrict__ gamma, const float* __restrict__ beta,
    const float* __restrict__ mean, const float* __restrict__ var,
    float* __restrict__ out)
{
    __shared__ float sp[256];    // pooled row for this graph
    __shared__ float pg[256];    // after Wl3
    __shared__ float h0[64], h1[64];
    const int g = blockIdx.x;
    const int t = threadIdx.x;
    const float inv = 1.0f / fmaxf(cnt[g], 1.0f);

    sp[t] = sums[g * 256 + t] * inv;
    __syncthreads();

    // Pg[t] = bl3[t] + sum_k sp[k] * Wl3[k*256+t]   (4 partials for ILP)
    {
        float a0 = 0.f, a1 = 0.f, a2 = 0.f, a3 = 0.f;
        #pragma unroll 4
        for (int k = 0; k < 256; k += 4) {
            a0 += sp[k + 0] * Wl3[(k + 0) * 256 + t];
            a1 += sp[k + 1] * Wl3[(k + 1) * 256 + t];
            a2 += sp[k + 2] * Wl3[(k + 2) * 256 + t];
            a3 += sp[k + 3] * Wl3[(k + 3) * 256 + t];
        }
        pg[t] = bl3[t] + ((a0 + a1) + (a2 + a3));
    }
    __syncthreads();

    // layer 1: 64 outputs, threads 0..63
    if (t < 64) {
        float a0 = 0.f, a1 = 0.f, a2 = 0.f, a3 = 0.f;
        #pragma unroll 4
        for (int k = 0; k < 256; k += 4) {
            a0 += pg[k + 0] * W1[(k + 0) * 64 + t];
            a1 += pg[k + 1] * W1[(k + 1) * 64 + t];
            a2 += pg[k + 2] * W1[(k + 2) * 64 + t];
            a3 += pg[k + 3] * W1[(k + 3) * 64 + t];
        }
        float acc = b1[t] + ((a0 + a1) + (a2 + a3));
        float sc = gamma[t] * rsqrtf(var[t] + 1e-5f);
        acc = (acc - mean[t]) * sc + beta[t];
        h0[t] = fmaxf(acc, 0.0f);
    }
    __syncthreads();

    for (int L = 0; L < 3; ++L) {
        const float* W  = Wh + L * 64 * 64;
        const float* hin  = (L & 1) ? h1 : h0;
        float*       hout = (L & 1) ? h0 : h1;
        if (t < 64) {
            const float* ga = gamma + (L + 1) * 64;
            const float* be = beta  + (L + 1) * 64;
            const float* me = mean  + (L + 1) * 64;
            const float* va = var   + (L + 1) * 64;
            float a0 = 0.f, a1 = 0.f, a2 = 0.f, a3 = 0.f;
            #pragma unroll 4
            for (int k = 0; k < 64; k += 4) {
                a0 += hin[k + 0] * W[(k + 0) * 64 + t];
                a1 += hin[k + 1] * W[(k + 1) * 64 + t];
                a2 += hin[k + 2] * W[(k + 2) * 64 + t];
                a3 += hin[k + 3] * W[(k + 3) * 64 + t];
            }
            float acc = (bh + L * 64)[t] + ((a0 + a1) + (a2 + a3));
            float sc = ga[t] * rsqrtf(va[t] + 1e-5f);
            acc = (acc - me[t]) * sc + be[t];
            hout[t] = fmaxf(acc, 0.0f);
        }
        __syncthreads();
    }

    if (t < 8) {
        const float* hf = h1;   // after L=2, output in h1
        float acc = bo[t];
        for (int k = 0; k < 64; ++k) acc += hf[k] * Wo[k * 8 + t];
        out[g * 8 + t] = acc;
    }
}

extern "C" void kernel_launch(void* const* d_in, const int* in_sizes, int n_in,
                              void* d_out, int out_size, void* d_ws, size_t ws_size,
                              hipStream_t stream)
{
    const int N = GN_N, E = GN_E;
    const float* x          = (const float*)d_in[0];
    const int*   edge_index = (const int*)d_in[1];
    const int*   batch      = (const int*)d_in[2];
    const int*   src = edge_index;
    const int*   dst = edge_index + E;
    auto F = [&](int i) { return (const float*)d_in[i]; };

    // ---- workspace layout ----
    float* ws    = (float*)d_ws;
    float* G     = ws;                          // N x 256  [K|Q|V|S]
    float* hA    = G  + (size_t)N * 256;        // N x 64
    float* hB    = hA + (size_t)N * 64;         // N x 128
    float* sums  = hB + (size_t)N * 128;        // 32 x 256
    float* cnt   = sums + GN_G * 256;           // 32
    float* bcat  = cnt + GN_G;                  // 7 x 256
    ushort* Whi  = (ushort*)(bcat + 1792);
    ushort* Wlo  = Whi + W_TOTAL;
    int* deg     = (int*)(Wlo + W_TOTAL);
    int* cursor  = deg + N;
    int* row_ptr = cursor + N;                  // N+1
    int* elist   = row_ptr + (N + 1);           // E
    int* bsums   = elist + E;                   // 512
    int* se      = bsums + 512;                 // 64

    size_t need = (size_t)((char*)(se + 64) - (char*)ws);
    if (ws_size < need) return;

    // ---- CSR build + graph bounds ----
    const int eb = (E + 255) / 256;
    const int nb = (N + 255) / 256;
    zero_int<<<nb, 256, 0, stream>>>(deg, N);
    zero_int<<<1, 256, 0, stream>>>(se, 64);
    hist_kernel<<<eb, 256, 0, stream>>>(dst, deg);
    scan1<<<nb, 256, 0, stream>>>(deg, row_ptr, bsums);
    scan2<<<1, 512, 0, stream>>>(bsums, nb);
    scan3<<<nb, 256, 0, stream>>>(bsums, row_ptr, cursor);
    scatter_kernel<<<eb, 256, 0, stream>>>(src, dst, cursor, elist);
    bounds_kernel<<<nb, 256, 0, stream>>>(batch, se);
    cnt_kernel<<<1, 64, 0, stream>>>(se, cnt);

    // ---- weight pre-conversion ----
    WSrc S;
    for (int l = 0; l < 3; ++l) {
        int base = 3 + l * 10;
        for (int g = 0; g < 4; ++g) S.Wg[l][g] = F(base + g);
        for (int g = 0; g < 4; ++g) S.bg[l][g] = F(base + 4 + g);
    }
    S.Wl[0] = F(11); S.Wl[1] = F(21);
    wconv<<<(W_TOTAL + 1792 + 255) / 256, 256, 0, stream>>>(S, Whi, Wlo, bcat);

    zero_sums<<<(GN_G * 256 + 255) / 256, 256, 0, stream>>>(sums);

    // ---- layers ----
    const int rb = (N + 127) / 128;
    const int gatherBlocks = (N + 3) / 4;

    struct LCfg { const float* hin; int lda, K, nch; size_t goff, gstride; int bchunk; };
    LCfg L[3] = {
        { x,  128, 128, 1, 0,        0,     0 },
        { hA,  64,  64, 2, WOFF_L2,  16384, 1 },
        { hB, 128, 128, 4, WOFF_L3,  32768, 3 },
    };

    for (int l = 0; l < 3; ++l) {
        for (int ch = 0; ch < L[l].nch; ++ch) {
            size_t go = L[l].goff + (size_t)ch * L[l].gstride;
            gemm_bf3<128><<<dim3(rb, 2), 256, 0, stream>>>(
                L[l].hin, L[l].lda, Whi + go, Wlo + go,
                bcat + (size_t)(L[l].bchunk + ch) * 256, G, 256, L[l].K, 0, 0);

            if (l == 0) {
                edge_gather<<<gatherBlocks, 256, 0, stream>>>(G, row_ptr, elist);
                gemm_bf3<64><<<dim3(rb, 1), 256, 0, stream>>>(
                    G + 192, 256, Whi + WOFF_WL1, Wlo + WOFF_WL1,
                    F(12), hA, 64, 64, 1, 0);
            } else if (l == 1) {
                edge_gather<<<gatherBlocks, 256, 0, stream>>>(G, row_ptr, elist);
                gemm_bf3<128><<<dim3(rb, 1), 256, 0, stream>>>(
                    G + 192, 256, Whi + WOFF_WL2 + (size_t)ch * 8192,
                    Wlo + WOFF_WL2 + (size_t)ch * 8192,
                    F(22), hB, 128, 64, 1, ch > 0);
            } else {
                edge_gather_pool<<<gatherBlocks, 256, 0, stream>>>(
                    G, row_ptr, elist, batch, sums, ch * 64);
            }
        }
    }

    mlp_kernel<<<GN_G, 256, 0, stream>>>(sums, cnt, F(31), F(32),
                                         F(33), F(34), F(35), F(36), F(37), F(38),
                                         F(39), F(40), F(41), F(42),
                                         (float*)d_out);
}

// Round 7
// 1196.018 us; speedup vs baseline: 2.8144x; 1.0919x over previous
//
#include <hip/hip_runtime.h>
#include <hip/hip_bf16.h>

// ---------------------------------------------------------------------------
// QuadraticGNN: 3x ResGatedGraphConv (ReLU gate, LeakyReLU 0.01, linear Wl)
//               -> global mean pool (32 graphs) -> 5-layer MLP with BN.
// Round 6:
//   - Gather kernels restructured for memory-level parallelism: edges
//     processed in batches of 4 (8 independent Q/V loads in flight vs 2).
//     Was latency-bound: 7.6% VALU, 11% HBM, ~2 dependent round-trips/edge.
//   - Rest as round 5 (MFMA bf16x3 GEMMs, CSR gather, fused layer-3 pool,
//     per-graph MLP blocks).
// ---------------------------------------------------------------------------

#define GN_N 100000
#define GN_E 300000
#define GN_G 32

typedef __attribute__((ext_vector_type(8))) short short8;
typedef __attribute__((ext_vector_type(4))) float floatx4;

__device__ inline ushort f2bf_rne(float f) {
    unsigned u = __float_as_uint(f);
    unsigned r = u + 0x7fffu + ((u >> 16) & 1u);
    return (ushort)(r >> 16);
}
__device__ inline float bf2f(ushort h) { return __uint_as_float(((unsigned)h) << 16); }

// W-array layout (ushort offsets), k-major [col][K] per segment.
#define WOFF_L2   32768
#define WOFF_L3   65536
#define WOFF_WL1  196608
#define WOFF_WL2  200704
#define W_TOTAL   217088

struct WSrc {
    const float* Wg[3][4];
    const float* Wl[2];
    const float* bg[3][4];
};

__global__ void wconv(WSrc S, ushort* __restrict__ hi, ushort* __restrict__ lo,
                      float* __restrict__ biascat)
{
    int id = blockIdx.x * 256 + threadIdx.x;
    if (id < 196608) {
        int l, base, ci, co;
        if (id < 32768)      { l = 0; base = 0;        ci = 128; co = 64;  }
        else if (id < 65536) { l = 1; base = WOFF_L2;  ci = 64;  co = 128; }
        else                 { l = 2; base = WOFF_L3;  ci = 128; co = 256; }
        int r  = id - base;
        int g  = r / (co * ci);
        int r2 = r - g * co * ci;
        int c  = r2 / ci;
        int k  = r2 - c * ci;
        float v = S.Wg[l][g][k * co + c];
        int ch  = c >> 6;
        int dst = base + ch * (256 * ci) + (((g << 6) + (c & 63)) * ci) + k;
        ushort h = f2bf_rne(v);
        hi[dst] = h; lo[dst] = f2bf_rne(v - bf2f(h));
    } else if (id < 196608 + 4096) {
        int r = id - 196608;
        int c = r >> 6, k = r & 63;
        float v = S.Wl[0][k * 64 + c];
        int dst = WOFF_WL1 + c * 64 + k;
        ushort h = f2bf_rne(v);
        hi[dst] = h; lo[dst] = f2bf_rne(v - bf2f(h));
    } else if (id < W_TOTAL) {
        int r = id - WOFF_WL2;
        int ch = r >> 13, r2 = r & 8191;
        int c = r2 >> 6, k = r2 & 63;
        float v = S.Wl[1][(ch * 64 + k) * 128 + c];
        int dst = WOFF_WL2 + ch * 8192 + c * 64 + k;
        ushort h = f2bf_rne(v);
        hi[dst] = h; lo[dst] = f2bf_rne(v - bf2f(h));
    } else if (id < W_TOTAL + 1792) {
        int i = id - W_TOTAL;
        int chunk = i >> 8, c = i & 255;
        int g = c >> 6, cc = c & 63;
        const int ltab[7] = {0, 1, 1, 2, 2, 2, 2};
        const int ctab[7] = {0, 0, 64, 0, 64, 128, 192};
        biascat[i] = S.bg[ltab[chunk]][g][ctab[chunk] + cc];
    }
}

// C[N, BC*gridDim.y] (+)= act(A)[N,K] @ B[K, cols] (+ bias)
template<int BC>
__global__ __launch_bounds__(256) void gemm_bf3(
    const float* __restrict__ A, int lda,
    const ushort* __restrict__ Bh, const ushort* __restrict__ Bl,
    const float* __restrict__ bias,
    float* __restrict__ C, int ldc,
    int K, int leaky, int accum)
{
    constexpr int RT = (BC == 128) ? 4 : 2;
    __shared__ ushort sAh[128][40], sAl[128][40];
    __shared__ ushort sBh[BC][40],  sBl[BC][40];

    const int tid  = threadIdx.x;
    const int w    = tid >> 6, lane = tid & 63;
    const int m    = lane & 15, quad = lane >> 4;
    const int row0 = blockIdx.x * 128;
    const int col0 = blockIdx.y * BC;
    const int wr   = (BC == 128) ? (w >> 1) * 64 : w * 32;
    const int wc   = (BC == 128) ? (w & 1) * 64 : 0;

    floatx4 acc[RT][4];
    #pragma unroll
    for (int i = 0; i < RT; ++i)
        #pragma unroll
        for (int j = 0; j < 4; ++j) acc[i][j] = (floatx4){0.f, 0.f, 0.f, 0.f};

    const int ar = tid >> 1;
    const int ak = (tid & 1) * 16;

    for (int k0 = 0; k0 < K; k0 += 32) {
        {
            float av[16];
            int arow = row0 + ar;
            if (arow < GN_N) {
                const float* ap = A + (size_t)arow * lda + k0 + ak;
                #pragma unroll
                for (int j = 0; j < 4; ++j) {
                    float4 t = *(const float4*)(ap + j * 4);
                    av[j*4+0] = t.x; av[j*4+1] = t.y; av[j*4+2] = t.z; av[j*4+3] = t.w;
                }
            } else {
                #pragma unroll
                for (int j = 0; j < 16; ++j) av[j] = 0.f;
            }
            if (leaky) {
                #pragma unroll
                for (int j = 0; j < 16; ++j) av[j] = av[j] > 0.f ? av[j] : 0.01f * av[j];
            }
            short8 h0, h1, l0, l1;
            #pragma unroll
            for (int j = 0; j < 8; ++j) {
                ushort h = f2bf_rne(av[j]);
                h0[j] = (short)h; l0[j] = (short)f2bf_rne(av[j] - bf2f(h));
            }
            #pragma unroll
            for (int j = 0; j < 8; ++j) {
                ushort h = f2bf_rne(av[8 + j]);
                h1[j] = (short)h; l1[j] = (short)f2bf_rne(av[8 + j] - bf2f(h));
            }
            *(short8*)&sAh[ar][ak]     = h0;  *(short8*)&sAh[ar][ak + 8] = h1;
            *(short8*)&sAl[ar][ak]     = l0;  *(short8*)&sAl[ar][ak + 8] = l1;
        }
        if (BC == 128) {
            int col = tid >> 1, bk = (tid & 1) * 16;
            size_t off = (size_t)(col0 + col) * K + k0 + bk;
            *(short8*)&sBh[col][bk]     = *(const short8*)(Bh + off);
            *(short8*)&sBh[col][bk + 8] = *(const short8*)(Bh + off + 8);
            *(short8*)&sBl[col][bk]     = *(const short8*)(Bl + off);
            *(short8*)&sBl[col][bk + 8] = *(const short8*)(Bl + off + 8);
        } else {
            int col = tid >> 2, bk = (tid & 3) * 8;
            size_t off = (size_t)(col0 + col) * K + k0 + bk;
            *(short8*)&sBh[col][bk] = *(const short8*)(Bh + off);
            *(short8*)&sBl[col][bk] = *(const short8*)(Bl + off);
        }
        __syncthreads();
        short8 bhf[4], blf[4];
        #pragma unroll
        for (int ct = 0; ct < 4; ++ct) {
            bhf[ct] = *(const short8*)&sBh[wc + ct * 16 + m][quad * 8];
            blf[ct] = *(const short8*)&sBl[wc + ct * 16 + m][quad * 8];
        }
        #pragma unroll
        for (int rt = 0; rt < RT; ++rt) {
            short8 ahf = *(const short8*)&sAh[wr + rt * 16 + m][quad * 8];
            short8 alf = *(const short8*)&sAl[wr + rt * 16 + m][quad * 8];
            #pragma unroll
            for (int ct = 0; ct < 4; ++ct) {
                acc[rt][ct] = __builtin_amdgcn_mfma_f32_16x16x32_bf16(ahf, bhf[ct], acc[rt][ct], 0, 0, 0);
                acc[rt][ct] = __builtin_amdgcn_mfma_f32_16x16x32_bf16(ahf, blf[ct], acc[rt][ct], 0, 0, 0);
                acc[rt][ct] = __builtin_amdgcn_mfma_f32_16x16x32_bf16(alf, bhf[ct], acc[rt][ct], 0, 0, 0);
            }
        }
        __syncthreads();
    }

    #pragma unroll
    for (int rt = 0; rt < RT; ++rt) {
        #pragma unroll
        for (int ct = 0; ct < 4; ++ct) {
            int ocol = col0 + wc + ct * 16 + m;
            #pragma unroll
            for (int reg = 0; reg < 4; ++reg) {
                int orow = row0 + wr + rt * 16 + quad * 4 + reg;
                if (orow < GN_N) {
                    float v = acc[rt][ct][reg];
                    if (accum) v += C[(size_t)orow * ldc + ocol];
                    else       v += bias[ocol];
                    C[(size_t)orow * ldc + ocol] = v;
                }
            }
        }
    }
}

// ---------------- CSR build ----------------
__global__ void zero_int(int* p, int n)
{
    int i = blockIdx.x * 256 + threadIdx.x;
    if (i < n) p[i] = 0;
}

__global__ void hist_kernel(const int* __restrict__ dst, int* __restrict__ deg)
{
    int e = blockIdx.x * 256 + threadIdx.x;
    if (e < GN_E) atomicAdd(&deg[dst[e]], 1);
}

__global__ void scan1(const int* __restrict__ deg, int* __restrict__ rp, int* __restrict__ bsums)
{
    __shared__ int s[256];
    int b = blockIdx.x, t = threadIdx.x;
    int i = b * 256 + t;
    int v = (i < GN_N) ? deg[i] : 0;
    s[t] = v;
    __syncthreads();
    for (int off = 1; off < 256; off <<= 1) {
        int x = (t >= off) ? s[t - off] : 0;
        __syncthreads();
        s[t] += x;
        __syncthreads();
    }
    if (i < GN_N) rp[i] = s[t] - v;
    if (t == 255) bsums[b] = s[255];
}

__global__ __launch_bounds__(512) void scan2(int* bsums, int nb)
{
    __shared__ int s[512];
    int t = threadIdx.x;
    int v = (t < nb) ? bsums[t] : 0;
    s[t] = v;
    __syncthreads();
    for (int off = 1; off < 512; off <<= 1) {
        int x = (t >= off) ? s[t - off] : 0;
        __syncthreads();
        s[t] += x;
        __syncthreads();
    }
    if (t < nb) bsums[t] = s[t] - v;
}

__global__ void scan3(const int* __restrict__ bsums, int* __restrict__ rp, int* __restrict__ cursor)
{
    int b = blockIdx.x, t = threadIdx.x;
    int i = b * 256 + t;
    if (i < GN_N) {
        int v = rp[i] + bsums[b];
        rp[i] = v; cursor[i] = v;
    }
    if (i == 0) rp[GN_N] = GN_E;
}

__global__ void scatter_kernel(
    const int* __restrict__ src, const int* __restrict__ dst,
    int* __restrict__ cursor, int* __restrict__ elist)
{
    int e = blockIdx.x * 256 + threadIdx.x;
    if (e >= GN_E) return;
    int d = dst[e];
    int pos = atomicAdd(&cursor[d], 1);
    elist[pos] = src[e];
}

// Graph segment boundaries on sorted batch -> se[0..31]=start, se[32..63]=end.
__global__ void bounds_kernel(const int* __restrict__ batch, int* __restrict__ se)
{
    int i = blockIdx.x * 256 + threadIdx.x;
    if (i >= GN_N) return;
    int g = batch[i];
    if (i == 0 || batch[i - 1] != g) se[g] = i;
    if (i == GN_N - 1 || batch[i + 1] != g) se[32 + g] = i + 1;
}

__global__ void cnt_kernel(const int* __restrict__ se, float* __restrict__ cnt)
{
    int g = threadIdx.x;
    if (g < GN_G) cnt[g] = (float)(se[32 + g] - se[g]);
}

// agg(S-section) = S + sum_{s->node} relu(K[node]+Q[s])*V[s], in-place on G.
// 4-edge batches: 8 independent Q/V loads in flight (latency hiding).
__global__ __launch_bounds__(256) void edge_gather(
    float* __restrict__ G,
    const int* __restrict__ row_ptr, const int* __restrict__ elist)
{
    int node = blockIdx.x * 4 + (threadIdx.x >> 6);
    if (node >= GN_N) return;
    int c = threadIdx.x & 63;
    int beg = row_ptr[node], end = row_ptr[node + 1];
    const float* Gq = G + 64 + c;
    const float* Gv = G + 128 + c;
    float k   = G[(size_t)node * 256 + c];
    float acc = G[(size_t)node * 256 + 192 + c];
    for (int i = beg; i < end; i += 4) {
        int n = end - i;
        int j1 = i + (1 < n ? 1 : 0);
        int j2 = i + (2 < n ? 2 : 0);
        int j3 = i + (3 < n ? 3 : 0);
        int s0 = elist[i],  s1 = elist[j1];
        int s2 = elist[j2], s3 = elist[j3];
        float q0 = Gq[(size_t)s0 * 256], q1 = Gq[(size_t)s1 * 256];
        float q2 = Gq[(size_t)s2 * 256], q3 = Gq[(size_t)s3 * 256];
        float v0 = Gv[(size_t)s0 * 256], v1 = Gv[(size_t)s1 * 256];
        float v2 = Gv[(size_t)s2 * 256], v3 = Gv[(size_t)s3 * 256];
        float g0 = k + q0, g1 = k + q1, g2 = k + q2, g3 = k + q3;
        if (g0 > 0.f)          acc += g0 * v0;
        if (n > 1 && g1 > 0.f) acc += g1 * v1;
        if (n > 2 && g2 > 0.f) acc += g2 * v2;
        if (n > 3 && g3 > 0.f) acc += g3 * v3;
    }
    G[(size_t)node * 256 + 192 + c] = acc;
}

// Layer-3: gather + leaky + block-reduced mean-pool accumulate. No G write.
__global__ __launch_bounds__(256) void edge_gather_pool(
    const float* __restrict__ G,
    const int* __restrict__ row_ptr, const int* __restrict__ elist,
    const int* __restrict__ batch,
    float* __restrict__ sums, int c0)
{
    __shared__ float red[4][64];
    __shared__ int gid[4];
    int w = threadIdx.x >> 6, c = threadIdx.x & 63;
    int node = blockIdx.x * 4 + w;
    float acc = 0.f;
    int g = -1;
    if (node < GN_N) {
        g = batch[node];
        int beg = row_ptr[node], end = row_ptr[node + 1];
        const float* Gq = G + 64 + c;
        const float* Gv = G + 128 + c;
        float k = G[(size_t)node * 256 + c];
        acc = G[(size_t)node * 256 + 192 + c];
        for (int i = beg; i < end; i += 4) {
            int n = end - i;
            int j1 = i + (1 < n ? 1 : 0);
            int j2 = i + (2 < n ? 2 : 0);
            int j3 = i + (3 < n ? 3 : 0);
            int s0 = elist[i],  s1 = elist[j1];
            int s2 = elist[j2], s3 = elist[j3];
            float q0 = Gq[(size_t)s0 * 256], q1 = Gq[(size_t)s1 * 256];
            float q2 = Gq[(size_t)s2 * 256], q3 = Gq[(size_t)s3 * 256];
            float v0 = Gv[(size_t)s0 * 256], v1 = Gv[(size_t)s1 * 256];
            float v2 = Gv[(size_t)s2 * 256], v3 = Gv[(size_t)s3 * 256];
            float g0 = k + q0, g1 = k + q1, g2 = k + q2, g3 = k + q3;
            if (g0 > 0.f)          acc += g0 * v0;
            if (n > 1 && g1 > 0.f) acc += g1 * v1;
            if (n > 2 && g2 > 0.f) acc += g2 * v2;
            if (n > 3 && g3 > 0.f) acc += g3 * v3;
        }
        acc = acc > 0.f ? acc : 0.01f * acc;   // leaky
    }
    red[w][c] = acc;
    if (c == 0) gid[w] = g;
    __syncthreads();
    if (w == 0) {
        int i = 0;
        while (i < 4) {
            int gg = gid[i];
            float s = 0.f;
            int j = i;
            while (j < 4 && gid[j] == gg) { s += red[j][c]; ++j; }
            if (gg >= 0) atomicAdd(&sums[gg * 256 + c0 + c], s);
            i = j;
        }
    }
}

__global__ void zero_sums(float* sums)
{
    int i = blockIdx.x * 256 + threadIdx.x;
    if (i < GN_G * 256) sums[i] = 0.0f;
}

// One block per graph: Pl = sums[g]/cnt[g]; Pg = Pl @ Wl3 + bl3; BN-MLP chain.
__global__ __launch_bounds__(256) void mlp_kernel(
    const float* __restrict__ sums, const float* __restrict__ cnt,
    const float* __restrict__ Wl3, const float* __restrict__ bl3,
    const float* __restrict__ W1, const float* __restrict__ b1,
    const float* __restrict__ Wh, const float* __restrict__ bh,
    const float* __restrict__ Wo, const float* __restrict__ bo,
    const float* __restrict__ gamma, const float* __restrict__ beta,
    const float* __restrict__ mean, const float* __restrict__ var,
    float* __restrict__ out)
{
    __shared__ float sp[256];
    __shared__ float pg[256];
    __shared__ float h0[64], h1[64];
    const int g = blockIdx.x;
    const int t = threadIdx.x;
    const float inv = 1.0f / fmaxf(cnt[g], 1.0f);

    sp[t] = sums[g * 256 + t] * inv;
    __syncthreads();

    {
        float a0 = 0.f, a1 = 0.f, a2 = 0.f, a3 = 0.f;
        #pragma unroll 4
        for (int k = 0; k < 256; k += 4) {
            a0 += sp[k + 0] * Wl3[(k + 0) * 256 + t];
            a1 += sp[k + 1] * Wl3[(k + 1) * 256 + t];
            a2 += sp[k + 2] * Wl3[(k + 2) * 256 + t];
            a3 += sp[k + 3] * Wl3[(k + 3) * 256 + t];
        }
        pg[t] = bl3[t] + ((a0 + a1) + (a2 + a3));
    }
    __syncthreads();

    if (t < 64) {
        float a0 = 0.f, a1 = 0.f, a2 = 0.f, a3 = 0.f;
        #pragma unroll 4
        for (int k = 0; k < 256; k += 4) {
            a0 += pg[k + 0] * W1[(k + 0) * 64 + t];
            a1 += pg[k + 1] * W1[(k + 1) * 64 + t];
            a2 += pg[k + 2] * W1[(k + 2) * 64 + t];
            a3 += pg[k + 3] * W1[(k + 3) * 64 + t];
        }
        float acc = b1[t] + ((a0 + a1) + (a2 + a3));
        float sc = gamma[t] * rsqrtf(var[t] + 1e-5f);
        acc = (acc - mean[t]) * sc + beta[t];
        h0[t] = fmaxf(acc, 0.0f);
    }
    __syncthreads();

    for (int L = 0; L < 3; ++L) {
        const float* W  = Wh + L * 64 * 64;
        const float* hin  = (L & 1) ? h1 : h0;
        float*       hout = (L & 1) ? h0 : h1;
        if (t < 64) {
            const float* ga = gamma + (L + 1) * 64;
            const float* be = beta  + (L + 1) * 64;
            const float* me = mean  + (L + 1) * 64;
            const float* va = var   + (L + 1) * 64;
            float a0 = 0.f, a1 = 0.f, a2 = 0.f, a3 = 0.f;
            #pragma unroll 4
            for (int k = 0; k < 64; k += 4) {
                a0 += hin[k + 0] * W[(k + 0) * 64 + t];
                a1 += hin[k + 1] * W[(k + 1) * 64 + t];
                a2 += hin[k + 2] * W[(k + 2) * 64 + t];
                a3 += hin[k + 3] * W[(k + 3) * 64 + t];
            }
            float acc = (bh + L * 64)[t] + ((a0 + a1) + (a2 + a3));
            float sc = ga[t] * rsqrtf(va[t] + 1e-5f);
            acc = (acc - me[t]) * sc + be[t];
            hout[t] = fmaxf(acc, 0.0f);
        }
        __syncthreads();
    }

    if (t < 8) {
        const float* hf = h1;
        float acc = bo[t];
        for (int k = 0; k < 64; ++k) acc += hf[k] * Wo[k * 8 + t];
        out[g * 8 + t] = acc;
    }
}

extern "C" void kernel_launch(void* const* d_in, const int* in_sizes, int n_in,
                              void* d_out, int out_size, void* d_ws, size_t ws_size,
                              hipStream_t stream)
{
    const int N = GN_N, E = GN_E;
    const float* x          = (const float*)d_in[0];
    const int*   edge_index = (const int*)d_in[1];
    const int*   batch      = (const int*)d_in[2];
    const int*   src = edge_index;
    const int*   dst = edge_index + E;
    auto F = [&](int i) { return (const float*)d_in[i]; };

    // ---- workspace layout ----
    float* ws    = (float*)d_ws;
    float* G     = ws;                          // N x 256  [K|Q|V|S]
    float* hA    = G  + (size_t)N * 256;        // N x 64
    float* hB    = hA + (size_t)N * 64;         // N x 128
    float* sums  = hB + (size_t)N * 128;        // 32 x 256
    float* cnt   = sums + GN_G * 256;           // 32
    float* bcat  = cnt + GN_G;                  // 7 x 256
    ushort* Whi  = (ushort*)(bcat + 1792);
    ushort* Wlo  = Whi + W_TOTAL;
    int* deg     = (int*)(Wlo + W_TOTAL);
    int* cursor  = deg + N;
    int* row_ptr = cursor + N;                  // N+1
    int* elist   = row_ptr + (N + 1);           // E
    int* bsums   = elist + E;                   // 512
    int* se      = bsums + 512;                 // 64

    size_t need = (size_t)((char*)(se + 64) - (char*)ws);
    if (ws_size < need) return;

    // ---- CSR build + graph bounds ----
    const int eb = (E + 255) / 256;
    const int nb = (N + 255) / 256;
    zero_int<<<nb, 256, 0, stream>>>(deg, N);
    zero_int<<<1, 256, 0, stream>>>(se, 64);
    hist_kernel<<<eb, 256, 0, stream>>>(dst, deg);
    scan1<<<nb, 256, 0, stream>>>(deg, row_ptr, bsums);
    scan2<<<1, 512, 0, stream>>>(bsums, nb);
    scan3<<<nb, 256, 0, stream>>>(bsums, row_ptr, cursor);
    scatter_kernel<<<eb, 256, 0, stream>>>(src, dst, cursor, elist);
    bounds_kernel<<<nb, 256, 0, stream>>>(batch, se);
    cnt_kernel<<<1, 64, 0, stream>>>(se, cnt);

    // ---- weight pre-conversion ----
    WSrc S;
    for (int l = 0; l < 3; ++l) {
        int base = 3 + l * 10;
        for (int g = 0; g < 4; ++g) S.Wg[l][g] = F(base + g);
        for (int g = 0; g < 4; ++g) S.bg[l][g] = F(base + 4 + g);
    }
    S.Wl[0] = F(11); S.Wl[1] = F(21);
    wconv<<<(W_TOTAL + 1792 + 255) / 256, 256, 0, stream>>>(S, Whi, Wlo, bcat);

    zero_sums<<<(GN_G * 256 + 255) / 256, 256, 0, stream>>>(sums);

    // ---- layers ----
    const int rb = (N + 127) / 128;
    const int gatherBlocks = (N + 3) / 4;

    struct LCfg { const float* hin; int lda, K, nch; size_t goff, gstride; int bchunk; };
    LCfg L[3] = {
        { x,  128, 128, 1, 0,        0,     0 },
        { hA,  64,  64, 2, WOFF_L2,  16384, 1 },
        { hB, 128, 128, 4, WOFF_L3,  32768, 3 },
    };

    for (int l = 0; l < 3; ++l) {
        for (int ch = 0; ch < L[l].nch; ++ch) {
            size_t go = L[l].goff + (size_t)ch * L[l].gstride;
            gemm_bf3<128><<<dim3(rb, 2), 256, 0, stream>>>(
                L[l].hin, L[l].lda, Whi + go, Wlo + go,
                bcat + (size_t)(L[l].bchunk + ch) * 256, G, 256, L[l].K, 0, 0);

            if (l == 0) {
                edge_gather<<<gatherBlocks, 256, 0, stream>>>(G, row_ptr, elist);
                gemm_bf3<64><<<dim3(rb, 1), 256, 0, stream>>>(
                    G + 192, 256, Whi + WOFF_WL1, Wlo + WOFF_WL1,
                    F(12), hA, 64, 64, 1, 0);
            } else if (l == 1) {
                edge_gather<<<gatherBlocks, 256, 0, stream>>>(G, row_ptr, elist);
                gemm_bf3<128><<<dim3(rb, 1), 256, 0, stream>>>(
                    G + 192, 256, Whi + WOFF_WL2 + (size_t)ch * 8192,
                    Wlo + WOFF_WL2 + (size_t)ch * 8192,
                    F(22), hB, 128, 64, 1, ch > 0);
            } else {
                edge_gather_pool<<<gatherBlocks, 256, 0, stream>>>(
                    G, row_ptr, elist, batch, sums, ch * 64);
            }
        }
    }

    mlp_kernel<<<GN_G, 256, 0, stream>>>(sums, cnt, F(31), F(32),
                                         F(33), F(34), F(35), F(36), F(37), F(38),
                                         F(39), F(40), F(41), F(42),
                                         (float*)d_out);
}

// Round 8
// 1011.535 us; speedup vs baseline: 3.3276x; 1.1824x over previous
//
#include <hip/hip_runtime.h>
#include <hip/hip_bf16.h>

// ---------------------------------------------------------------------------
// QuadraticGNN: 3x ResGatedGraphConv (ReLU gate, LeakyReLU 0.01, linear Wl)
//               -> global mean pool (32 graphs) -> 5-layer MLP with BN.
// Round 7:
//   - Gather kernels widened: 4 nodes per wave (16 per block). All 32 Q/V
//     loads issued before any use -> 4x memory-level parallelism per wave.
//     (Round-6 depth-batching didn't help: deg~3 => single iteration.)
//   - Rest as round 6 (MFMA bf16x3 GEMMs, CSR gather, fused layer-3 pool,
//     per-graph MLP blocks).
// ---------------------------------------------------------------------------

#define GN_N 100000
#define GN_E 300000
#define GN_G 32

typedef __attribute__((ext_vector_type(8))) short short8;
typedef __attribute__((ext_vector_type(4))) float floatx4;

__device__ inline ushort f2bf_rne(float f) {
    unsigned u = __float_as_uint(f);
    unsigned r = u + 0x7fffu + ((u >> 16) & 1u);
    return (ushort)(r >> 16);
}
__device__ inline float bf2f(ushort h) { return __uint_as_float(((unsigned)h) << 16); }

// W-array layout (ushort offsets), k-major [col][K] per segment.
#define WOFF_L2   32768
#define WOFF_L3   65536
#define WOFF_WL1  196608
#define WOFF_WL2  200704
#define W_TOTAL   217088

struct WSrc {
    const float* Wg[3][4];
    const float* Wl[2];
    const float* bg[3][4];
};

__global__ void wconv(WSrc S, ushort* __restrict__ hi, ushort* __restrict__ lo,
                      float* __restrict__ biascat)
{
    int id = blockIdx.x * 256 + threadIdx.x;
    if (id < 196608) {
        int l, base, ci, co;
        if (id < 32768)      { l = 0; base = 0;        ci = 128; co = 64;  }
        else if (id < 65536) { l = 1; base = WOFF_L2;  ci = 64;  co = 128; }
        else                 { l = 2; base = WOFF_L3;  ci = 128; co = 256; }
        int r  = id - base;
        int g  = r / (co * ci);
        int r2 = r - g * co * ci;
        int c  = r2 / ci;
        int k  = r2 - c * ci;
        float v = S.Wg[l][g][k * co + c];
        int ch  = c >> 6;
        int dst = base + ch * (256 * ci) + (((g << 6) + (c & 63)) * ci) + k;
        ushort h = f2bf_rne(v);
        hi[dst] = h; lo[dst] = f2bf_rne(v - bf2f(h));
    } else if (id < 196608 + 4096) {
        int r = id - 196608;
        int c = r >> 6, k = r & 63;
        float v = S.Wl[0][k * 64 + c];
        int dst = WOFF_WL1 + c * 64 + k;
        ushort h = f2bf_rne(v);
        hi[dst] = h; lo[dst] = f2bf_rne(v - bf2f(h));
    } else if (id < W_TOTAL) {
        int r = id - WOFF_WL2;
        int ch = r >> 13, r2 = r & 8191;
        int c = r2 >> 6, k = r2 & 63;
        float v = S.Wl[1][(ch * 64 + k) * 128 + c];
        int dst = WOFF_WL2 + ch * 8192 + c * 64 + k;
        ushort h = f2bf_rne(v);
        hi[dst] = h; lo[dst] = f2bf_rne(v - bf2f(h));
    } else if (id < W_TOTAL + 1792) {
        int i = id - W_TOTAL;
        int chunk = i >> 8, c = i & 255;
        int g = c >> 6, cc = c & 63;
        const int ltab[7] = {0, 1, 1, 2, 2, 2, 2};
        const int ctab[7] = {0, 0, 64, 0, 64, 128, 192};
        biascat[i] = S.bg[ltab[chunk]][g][ctab[chunk] + cc];
    }
}

// C[N, BC*gridDim.y] (+)= act(A)[N,K] @ B[K, cols] (+ bias)
template<int BC>
__global__ __launch_bounds__(256) void gemm_bf3(
    const float* __restrict__ A, int lda,
    const ushort* __restrict__ Bh, const ushort* __restrict__ Bl,
    const float* __restrict__ bias,
    float* __restrict__ C, int ldc,
    int K, int leaky, int accum)
{
    constexpr int RT = (BC == 128) ? 4 : 2;
    __shared__ ushort sAh[128][40], sAl[128][40];
    __shared__ ushort sBh[BC][40],  sBl[BC][40];

    const int tid  = threadIdx.x;
    const int w    = tid >> 6, lane = tid & 63;
    const int m    = lane & 15, quad = lane >> 4;
    const int row0 = blockIdx.x * 128;
    const int col0 = blockIdx.y * BC;
    const int wr   = (BC == 128) ? (w >> 1) * 64 : w * 32;
    const int wc   = (BC == 128) ? (w & 1) * 64 : 0;

    floatx4 acc[RT][4];
    #pragma unroll
    for (int i = 0; i < RT; ++i)
        #pragma unroll
        for (int j = 0; j < 4; ++j) acc[i][j] = (floatx4){0.f, 0.f, 0.f, 0.f};

    const int ar = tid >> 1;
    const int ak = (tid & 1) * 16;

    for (int k0 = 0; k0 < K; k0 += 32) {
        {
            float av[16];
            int arow = row0 + ar;
            if (arow < GN_N) {
                const float* ap = A + (size_t)arow * lda + k0 + ak;
                #pragma unroll
                for (int j = 0; j < 4; ++j) {
                    float4 t = *(const float4*)(ap + j * 4);
                    av[j*4+0] = t.x; av[j*4+1] = t.y; av[j*4+2] = t.z; av[j*4+3] = t.w;
                }
            } else {
                #pragma unroll
                for (int j = 0; j < 16; ++j) av[j] = 0.f;
            }
            if (leaky) {
                #pragma unroll
                for (int j = 0; j < 16; ++j) av[j] = av[j] > 0.f ? av[j] : 0.01f * av[j];
            }
            short8 h0, h1, l0, l1;
            #pragma unroll
            for (int j = 0; j < 8; ++j) {
                ushort h = f2bf_rne(av[j]);
                h0[j] = (short)h; l0[j] = (short)f2bf_rne(av[j] - bf2f(h));
            }
            #pragma unroll
            for (int j = 0; j < 8; ++j) {
                ushort h = f2bf_rne(av[8 + j]);
                h1[j] = (short)h; l1[j] = (short)f2bf_rne(av[8 + j] - bf2f(h));
            }
            *(short8*)&sAh[ar][ak]     = h0;  *(short8*)&sAh[ar][ak + 8] = h1;
            *(short8*)&sAl[ar][ak]     = l0;  *(short8*)&sAl[ar][ak + 8] = l1;
        }
        if (BC == 128) {
            int col = tid >> 1, bk = (tid & 1) * 16;
            size_t off = (size_t)(col0 + col) * K + k0 + bk;
            *(short8*)&sBh[col][bk]     = *(const short8*)(Bh + off);
            *(short8*)&sBh[col][bk + 8] = *(const short8*)(Bh + off + 8);
            *(short8*)&sBl[col][bk]     = *(const short8*)(Bl + off);
            *(short8*)&sBl[col][bk + 8] = *(const short8*)(Bl + off + 8);
        } else {
            int col = tid >> 2, bk = (tid & 3) * 8;
            size_t off = (size_t)(col0 + col) * K + k0 + bk;
            *(short8*)&sBh[col][bk] = *(const short8*)(Bh + off);
            *(short8*)&sBl[col][bk] = *(const short8*)(Bl + off);
        }
        __syncthreads();
        short8 bhf[4], blf[4];
        #pragma unroll
        for (int ct = 0; ct < 4; ++ct) {
            bhf[ct] = *(const short8*)&sBh[wc + ct * 16 + m][quad * 8];
            blf[ct] = *(const short8*)&sBl[wc + ct * 16 + m][quad * 8];
        }
        #pragma unroll
        for (int rt = 0; rt < RT; ++rt) {
            short8 ahf = *(const short8*)&sAh[wr + rt * 16 + m][quad * 8];
            short8 alf = *(const short8*)&sAl[wr + rt * 16 + m][quad * 8];
            #pragma unroll
            for (int ct = 0; ct < 4; ++ct) {
                acc[rt][ct] = __builtin_amdgcn_mfma_f32_16x16x32_bf16(ahf, bhf[ct], acc[rt][ct], 0, 0, 0);
                acc[rt][ct] = __builtin_amdgcn_mfma_f32_16x16x32_bf16(ahf, blf[ct], acc[rt][ct], 0, 0, 0);
                acc[rt][ct] = __builtin_amdgcn_mfma_f32_16x16x32_bf16(alf, bhf[ct], acc[rt][ct], 0, 0, 0);
            }
        }
        __syncthreads();
    }

    #pragma unroll
    for (int rt = 0; rt < RT; ++rt) {
        #pragma unroll
        for (int ct = 0; ct < 4; ++ct) {
            int ocol = col0 + wc + ct * 16 + m;
            #pragma unroll
            for (int reg = 0; reg < 4; ++reg) {
                int orow = row0 + wr + rt * 16 + quad * 4 + reg;
                if (orow < GN_N) {
                    float v = acc[rt][ct][reg];
                    if (accum) v += C[(size_t)orow * ldc + ocol];
                    else       v += bias[ocol];
                    C[(size_t)orow * ldc + ocol] = v;
                }
            }
        }
    }
}

// ---------------- CSR build ----------------
__global__ void zero_int(int* p, int n)
{
    int i = blockIdx.x * 256 + threadIdx.x;
    if (i < n) p[i] = 0;
}

__global__ void hist_kernel(const int* __restrict__ dst, int* __restrict__ deg)
{
    int e = blockIdx.x * 256 + threadIdx.x;
    if (e < GN_E) atomicAdd(&deg[dst[e]], 1);
}

__global__ void scan1(const int* __restrict__ deg, int* __restrict__ rp, int* __restrict__ bsums)
{
    __shared__ int s[256];
    int b = blockIdx.x, t = threadIdx.x;
    int i = b * 256 + t;
    int v = (i < GN_N) ? deg[i] : 0;
    s[t] = v;
    __syncthreads();
    for (int off = 1; off < 256; off <<= 1) {
        int x = (t >= off) ? s[t - off] : 0;
        __syncthreads();
        s[t] += x;
        __syncthreads();
    }
    if (i < GN_N) rp[i] = s[t] - v;
    if (t == 255) bsums[b] = s[255];
}

__global__ __launch_bounds__(512) void scan2(int* bsums, int nb)
{
    __shared__ int s[512];
    int t = threadIdx.x;
    int v = (t < nb) ? bsums[t] : 0;
    s[t] = v;
    __syncthreads();
    for (int off = 1; off < 512; off <<= 1) {
        int x = (t >= off) ? s[t - off] : 0;
        __syncthreads();
        s[t] += x;
        __syncthreads();
    }
    if (t < nb) bsums[t] = s[t] - v;
}

__global__ void scan3(const int* __restrict__ bsums, int* __restrict__ rp, int* __restrict__ cursor)
{
    int b = blockIdx.x, t = threadIdx.x;
    int i = b * 256 + t;
    if (i < GN_N) {
        int v = rp[i] + bsums[b];
        rp[i] = v; cursor[i] = v;
    }
    if (i == 0) rp[GN_N] = GN_E;
}

__global__ void scatter_kernel(
    const int* __restrict__ src, const int* __restrict__ dst,
    int* __restrict__ cursor, int* __restrict__ elist)
{
    int e = blockIdx.x * 256 + threadIdx.x;
    if (e >= GN_E) return;
    int d = dst[e];
    int pos = atomicAdd(&cursor[d], 1);
    elist[pos] = src[e];
}

// Graph segment boundaries on sorted batch -> se[0..31]=start, se[32..63]=end.
__global__ void bounds_kernel(const int* __restrict__ batch, int* __restrict__ se)
{
    int i = blockIdx.x * 256 + threadIdx.x;
    if (i >= GN_N) return;
    int g = batch[i];
    if (i == 0 || batch[i - 1] != g) se[g] = i;
    if (i == GN_N - 1 || batch[i + 1] != g) se[32 + g] = i + 1;
}

__global__ void cnt_kernel(const int* __restrict__ se, float* __restrict__ cnt)
{
    int g = threadIdx.x;
    if (g < GN_G) cnt[g] = (float)(se[32 + g] - se[g]);
}

// agg(S) = S + sum relu(K[d]+Q[s])*V[s], in-place. 4 nodes/wave, 16/block:
// up to 32 Q/V loads in flight per wave before any use.
__global__ __launch_bounds__(256) void edge_gather(
    float* __restrict__ G,
    const int* __restrict__ row_ptr, const int* __restrict__ elist)
{
    int w = threadIdx.x >> 6, c = threadIdx.x & 63;
    int n0 = blockIdx.x * 16 + w * 4;

    float k[4], acc[4];
    int beg[4], end[4];
    #pragma unroll
    for (int j = 0; j < 4; ++j) {
        int node = n0 + j;
        bool ok = node < GN_N;
        int nd = ok ? node : 0;
        beg[j] = row_ptr[nd];
        end[j] = ok ? row_ptr[nd + 1] : beg[j];
        k[j]   = G[(size_t)nd * 256 + c];
        acc[j] = G[(size_t)nd * 256 + 192 + c];
    }
    int s[16];
    #pragma unroll
    for (int j = 0; j < 4; ++j) {
        #pragma unroll
        for (int e = 0; e < 4; ++e) {
            int idx = beg[j] + e;
            s[j * 4 + e] = elist[idx < end[j] ? idx : 0];
        }
    }
    float q[16], v[16];
    #pragma unroll
    for (int je = 0; je < 16; ++je) {
        q[je] = G[(size_t)s[je] * 256 + 64 + c];
        v[je] = G[(size_t)s[je] * 256 + 128 + c];
    }
    #pragma unroll
    for (int j = 0; j < 4; ++j) {
        #pragma unroll
        for (int e = 0; e < 4; ++e) {
            if (beg[j] + e < end[j]) {
                float gt = k[j] + q[j * 4 + e];
                if (gt > 0.f) acc[j] += gt * v[j * 4 + e];
            }
        }
    }
    // tail: deg > 4 (rare, Poisson(3))
    #pragma unroll
    for (int j = 0; j < 4; ++j) {
        for (int i = beg[j] + 4; i < end[j]; ++i) {
            int ss = elist[i];
            float qq = G[(size_t)ss * 256 + 64 + c];
            float vv = G[(size_t)ss * 256 + 128 + c];
            float gt = k[j] + qq;
            if (gt > 0.f) acc[j] += gt * vv;
        }
    }
    #pragma unroll
    for (int j = 0; j < 4; ++j)
        if (n0 + j < GN_N) G[(size_t)(n0 + j) * 256 + 192 + c] = acc[j];
}

// Layer-3: same gather + leaky + 16-node LDS reduce + run-length atomics.
__global__ __launch_bounds__(256) void edge_gather_pool(
    const float* __restrict__ G,
    const int* __restrict__ row_ptr, const int* __restrict__ elist,
    const int* __restrict__ batch,
    float* __restrict__ sums, int c0)
{
    __shared__ float red[16][64];
    __shared__ int gid[16];
    int w = threadIdx.x >> 6, c = threadIdx.x & 63;
    int n0 = blockIdx.x * 16 + w * 4;

    float k[4], acc[4];
    int beg[4], end[4];
    #pragma unroll
    for (int j = 0; j < 4; ++j) {
        int node = n0 + j;
        bool ok = node < GN_N;
        int nd = ok ? node : 0;
        beg[j] = row_ptr[nd];
        end[j] = ok ? row_ptr[nd + 1] : beg[j];
        k[j]   = G[(size_t)nd * 256 + c];
        acc[j] = ok ? G[(size_t)nd * 256 + 192 + c] : 0.f;
    }
    int s[16];
    #pragma unroll
    for (int j = 0; j < 4; ++j) {
        #pragma unroll
        for (int e = 0; e < 4; ++e) {
            int idx = beg[j] + e;
            s[j * 4 + e] = elist[idx < end[j] ? idx : 0];
        }
    }
    float q[16], v[16];
    #pragma unroll
    for (int je = 0; je < 16; ++je) {
        q[je] = G[(size_t)s[je] * 256 + 64 + c];
        v[je] = G[(size_t)s[je] * 256 + 128 + c];
    }
    #pragma unroll
    for (int j = 0; j < 4; ++j) {
        #pragma unroll
        for (int e = 0; e < 4; ++e) {
            if (beg[j] + e < end[j]) {
                float gt = k[j] + q[j * 4 + e];
                if (gt > 0.f) acc[j] += gt * v[j * 4 + e];
            }
        }
    }
    #pragma unroll
    for (int j = 0; j < 4; ++j) {
        for (int i = beg[j] + 4; i < end[j]; ++i) {
            int ss = elist[i];
            float qq = G[(size_t)ss * 256 + 64 + c];
            float vv = G[(size_t)ss * 256 + 128 + c];
            float gt = k[j] + qq;
            if (gt > 0.f) acc[j] += gt * vv;
        }
    }
    #pragma unroll
    for (int j = 0; j < 4; ++j) {
        float a = acc[j];
        red[w * 4 + j][c] = a > 0.f ? a : 0.01f * a;   // leaky
    }
    if (c < 4) {
        int node = n0 + c;
        gid[w * 4 + c] = (node < GN_N) ? batch[node] : -1;
    }
    __syncthreads();
    if (w == 0) {
        int i = 0;
        while (i < 16) {
            int gg = gid[i];
            float sum = 0.f;
            int j = i;
            while (j < 16 && gid[j] == gg) { sum += red[j][c]; ++j; }
            if (gg >= 0) atomicAdd(&sums[gg * 256 + c0 + c], sum);
            i = j;
        }
    }
}

__global__ void zero_sums(float* sums)
{
    int i = blockIdx.x * 256 + threadIdx.x;
    if (i < GN_G * 256) sums[i] = 0.0f;
}

// One block per graph: Pl = sums[g]/cnt[g]; Pg = Pl @ Wl3 + bl3; BN-MLP chain.
__global__ __launch_bounds__(256) void mlp_kernel(
    const float* __restrict__ sums, const float* __restrict__ cnt,
    const float* __restrict__ Wl3, const float* __restrict__ bl3,
    const float* __restrict__ W1, const float* __restrict__ b1,
    const float* __restrict__ Wh, const float* __restrict__ bh,
    const float* __restrict__ Wo, const float* __restrict__ bo,
    const float* __restrict__ gamma, const float* __restrict__ beta,
    const float* __restrict__ mean, const float* __restrict__ var,
    float* __restrict__ out)
{
    __shared__ float sp[256];
    __shared__ float pg[256];
    __shared__ float h0[64], h1[64];
    const int g = blockIdx.x;
    const int t = threadIdx.x;
    const float inv = 1.0f / fmaxf(cnt[g], 1.0f);

    sp[t] = sums[g * 256 + t] * inv;
    __syncthreads();

    {
        float a0 = 0.f, a1 = 0.f, a2 = 0.f, a3 = 0.f;
        #pragma unroll 4
        for (int k = 0; k < 256; k += 4) {
            a0 += sp[k + 0] * Wl3[(k + 0) * 256 + t];
            a1 += sp[k + 1] * Wl3[(k + 1) * 256 + t];
            a2 += sp[k + 2] * Wl3[(k + 2) * 256 + t];
            a3 += sp[k + 3] * Wl3[(k + 3) * 256 + t];
        }
        pg[t] = bl3[t] + ((a0 + a1) + (a2 + a3));
    }
    __syncthreads();

    if (t < 64) {
        float a0 = 0.f, a1 = 0.f, a2 = 0.f, a3 = 0.f;
        #pragma unroll 4
        for (int k = 0; k < 256; k += 4) {
            a0 += pg[k + 0] * W1[(k + 0) * 64 + t];
            a1 += pg[k + 1] * W1[(k + 1) * 64 + t];
            a2 += pg[k + 2] * W1[(k + 2) * 64 + t];
            a3 += pg[k + 3] * W1[(k + 3) * 64 + t];
        }
        float acc = b1[t] + ((a0 + a1) + (a2 + a3));
        float sc = gamma[t] * rsqrtf(var[t] + 1e-5f);
        acc = (acc - mean[t]) * sc + beta[t];
        h0[t] = fmaxf(acc, 0.0f);
    }
    __syncthreads();

    for (int L = 0; L < 3; ++L) {
        const float* W  = Wh + L * 64 * 64;
        const float* hin  = (L & 1) ? h1 : h0;
        float*       hout = (L & 1) ? h0 : h1;
        if (t < 64) {
            const float* ga = gamma + (L + 1) * 64;
            const float* be = beta  + (L + 1) * 64;
            const float* me = mean  + (L + 1) * 64;
            const float* va = var   + (L + 1) * 64;
            float a0 = 0.f, a1 = 0.f, a2 = 0.f, a3 = 0.f;
            #pragma unroll 4
            for (int k = 0; k < 64; k += 4) {
                a0 += hin[k + 0] * W[(k + 0) * 64 + t];
                a1 += hin[k + 1] * W[(k + 1) * 64 + t];
                a2 += hin[k + 2] * W[(k + 2) * 64 + t];
                a3 += hin[k + 3] * W[(k + 3) * 64 + t];
            }
            float acc = (bh + L * 64)[t] + ((a0 + a1) + (a2 + a3));
            float sc = ga[t] * rsqrtf(va[t] + 1e-5f);
            acc = (acc - me[t]) * sc + be[t];
            hout[t] = fmaxf(acc, 0.0f);
        }
        __syncthreads();
    }

    if (t < 8) {
        const float* hf = h1;
        float acc = bo[t];
        for (int k = 0; k < 64; ++k) acc += hf[k] * Wo[k * 8 + t];
        out[g * 8 + t] = acc;
    }
}

extern "C" void kernel_launch(void* const* d_in, const int* in_sizes, int n_in,
                              void* d_out, int out_size, void* d_ws, size_t ws_size,
                              hipStream_t stream)
{
    const int N = GN_N, E = GN_E;
    const float* x          = (const float*)d_in[0];
    const int*   edge_index = (const int*)d_in[1];
    const int*   batch      = (const int*)d_in[2];
    const int*   src = edge_index;
    const int*   dst = edge_index + E;
    auto F = [&](int i) { return (const float*)d_in[i]; };

    // ---- workspace layout ----
    float* ws    = (float*)d_ws;
    float* G     = ws;                          // N x 256  [K|Q|V|S]
    float* hA    = G  + (size_t)N * 256;        // N x 64
    float* hB    = hA + (size_t)N * 64;         // N x 128
    float* sums  = hB + (size_t)N * 128;        // 32 x 256
    float* cnt   = sums + GN_G * 256;           // 32
    float* bcat  = cnt + GN_G;                  // 7 x 256
    ushort* Whi  = (ushort*)(bcat + 1792);
    ushort* Wlo  = Whi + W_TOTAL;
    int* deg     = (int*)(Wlo + W_TOTAL);
    int* cursor  = deg + N;
    int* row_ptr = cursor + N;                  // N+1
    int* elist   = row_ptr + (N + 1);           // E
    int* bsums   = elist + E;                   // 512
    int* se      = bsums + 512;                 // 64

    size_t need = (size_t)((char*)(se + 64) - (char*)ws);
    if (ws_size < need) return;

    // ---- CSR build + graph bounds ----
    const int eb = (E + 255) / 256;
    const int nb = (N + 255) / 256;
    zero_int<<<nb, 256, 0, stream>>>(deg, N);
    zero_int<<<1, 256, 0, stream>>>(se, 64);
    hist_kernel<<<eb, 256, 0, stream>>>(dst, deg);
    scan1<<<nb, 256, 0, stream>>>(deg, row_ptr, bsums);
    scan2<<<1, 512, 0, stream>>>(bsums, nb);
    scan3<<<nb, 256, 0, stream>>>(bsums, row_ptr, cursor);
    scatter_kernel<<<eb, 256, 0, stream>>>(src, dst, cursor, elist);
    bounds_kernel<<<nb, 256, 0, stream>>>(batch, se);
    cnt_kernel<<<1, 64, 0, stream>>>(se, cnt);

    // ---- weight pre-conversion ----
    WSrc S;
    for (int l = 0; l < 3; ++l) {
        int base = 3 + l * 10;
        for (int g = 0; g < 4; ++g) S.Wg[l][g] = F(base + g);
        for (int g = 0; g < 4; ++g) S.bg[l][g] = F(base + 4 + g);
    }
    S.Wl[0] = F(11); S.Wl[1] = F(21);
    wconv<<<(W_TOTAL + 1792 + 255) / 256, 256, 0, stream>>>(S, Whi, Wlo, bcat);

    zero_sums<<<(GN_G * 256 + 255) / 256, 256, 0, stream>>>(sums);

    // ---- layers ----
    const int rb = (N + 127) / 128;
    const int gatherBlocks = (N + 15) / 16;   // 6250

    struct LCfg { const float* hin; int lda, K, nch; size_t goff, gstride; int bchunk; };
    LCfg L[3] = {
        { x,  128, 128, 1, 0,        0,     0 },
        { hA,  64,  64, 2, WOFF_L2,  16384, 1 },
        { hB, 128, 128, 4, WOFF_L3,  32768, 3 },
    };

    for (int l = 0; l < 3; ++l) {
        for (int ch = 0; ch < L[l].nch; ++ch) {
            size_t go = L[l].goff + (size_t)ch * L[l].gstride;
            gemm_bf3<128><<<dim3(rb, 2), 256, 0, stream>>>(
                L[l].hin, L[l].lda, Whi + go, Wlo + go,
                bcat + (size_t)(L[l].bchunk + ch) * 256, G, 256, L[l].K, 0, 0);

            if (l == 0) {
                edge_gather<<<gatherBlocks, 256, 0, stream>>>(G, row_ptr, elist);
                gemm_bf3<64><<<dim3(rb, 1), 256, 0, stream>>>(
                    G + 192, 256, Whi + WOFF_WL1, Wlo + WOFF_WL1,
                    F(12), hA, 64, 64, 1, 0);
            } else if (l == 1) {
                edge_gather<<<gatherBlocks, 256, 0, stream>>>(G, row_ptr, elist);
                gemm_bf3<128><<<dim3(rb, 1), 256, 0, stream>>>(
                    G + 192, 256, Whi + WOFF_WL2 + (size_t)ch * 8192,
                    Wlo + WOFF_WL2 + (size_t)ch * 8192,
                    F(22), hB, 128, 64, 1, ch > 0);
            } else {
                edge_gather_pool<<<gatherBlocks, 256, 0, stream>>>(
                    G, row_ptr, elist, batch, sums, ch * 64);
            }
        }
    }

    mlp_kernel<<<GN_G, 256, 0, stream>>>(sums, cnt, F(31), F(32),
                                         F(33), F(34), F(35), F(36), F(37), F(38),
                                         F(39), F(40), F(41), F(42),
                                         (float*)d_out);
}